// Round 7
// baseline (854.375 us; speedup 1.0000x reference)
//
#include <hip/hip_runtime.h>

#define N_NODES 100000
#define N_EDGES 1600000
#define N_GRAPHS 512
#define F_IN 64
#define HD 256
#define EXTRA 16
#define SCAN_BLOCK 512
#define EDGE_BLOCKS 6250  // (N_EDGES+255)/256

typedef float f32x4 __attribute__((ext_vector_type(4)));
typedef _Float16 f16x4 __attribute__((ext_vector_type(4)));
typedef _Float16 f16x8 __attribute__((ext_vector_type(8)));

__device__ __forceinline__ float selu_f(float x) {
    const float a = 1.6732632423543772f, sc = 1.0507009873554805f;
    return x > 0.f ? sc * x : sc * a * (__expf(x) - 1.f);
}

// ---------------- CSR build ----------------
__global__ __launch_bounds__(SCAN_BLOCK) void scan1_k(const int* __restrict__ hist,
                                                      int* __restrict__ row_ptr,
                                                      int* __restrict__ bsums) {
    __shared__ int sm[SCAN_BLOCK];
    int t = threadIdx.x;
    int i = blockIdx.x * SCAN_BLOCK + t;
    int v = (i < N_NODES) ? hist[i] : 0;
    sm[t] = v;
    __syncthreads();
    for (int off = 1; off < SCAN_BLOCK; off <<= 1) {
        int add = (t >= off) ? sm[t - off] : 0;
        __syncthreads();
        sm[t] += add;
        __syncthreads();
    }
    if (i < N_NODES) row_ptr[i] = sm[t] - v;
    if (t == SCAN_BLOCK - 1) bsums[blockIdx.x] = sm[t];
}

// merged scan2+scan3: each block re-scans the (<=256) block sums in LDS,
// finalizes row_ptr AND initializes cursor = row_ptr.
__global__ __launch_bounds__(256) void scan23_k(int* __restrict__ row_ptr, const int* __restrict__ bsums,
                                                int* __restrict__ cursor, int nb) {
    __shared__ int bs[256];
    int t = threadIdx.x;
    bs[t] = (t < nb) ? bsums[t] : 0;
    __syncthreads();
    for (int off = 1; off < 256; off <<= 1) {
        int add = (t >= off) ? bs[t - off] : 0;
        __syncthreads();
        bs[t] += add;
        __syncthreads();
    }
    int i = blockIdx.x * 256 + t;
    if (i < N_NODES) {
        int b = i / SCAN_BLOCK;
        int p = b > 0 ? bs[b - 1] : 0;
        int r = row_ptr[i] + p;
        row_ptr[i] = r;
        cursor[i] = r;
    }
    if (i == 0) row_ptr[N_NODES] = N_EDGES;
}

// ---------------- fused: hist (random atomics, LDS-free) || weight splits + graph bounds ----------------
__device__ __forceinline__ void wsplit(const float* __restrict__ W, _Float16* __restrict__ Wh,
                                       _Float16* __restrict__ Wl, int idx, int K) {
    int n = idx / K, k = idx - n * K;
    float w = W[(size_t)k * HD + n];
    _Float16 hi = (_Float16)w;
    Wh[idx] = hi;
    Wl[idx] = (_Float16)(w - (float)hi);
}

__global__ __launch_bounds__(256) void histprep_k(const int* __restrict__ dst, int* __restrict__ hist,
                                                  const float* __restrict__ W1,
                                                  const float* __restrict__ W2,
                                                  const float* __restrict__ W3,
                                                  _Float16* __restrict__ W1h, _Float16* __restrict__ W1l,
                                                  _Float16* __restrict__ W2h, _Float16* __restrict__ W2l,
                                                  _Float16* __restrict__ W3h, _Float16* __restrict__ W3l,
                                                  const int* __restrict__ node_graph,
                                                  int* __restrict__ gstart) {
    int bid = blockIdx.x, t = threadIdx.x;
    if (bid < EDGE_BLOCKS) {
        int j = bid * 256 + t;
        if (j < N_EDGES) atomicAdd(&hist[dst[j]], 1);
        return;
    }
    int b = bid - EDGE_BLOCKS;
    if (b < 64) {
        wsplit(W1, W1h, W1l, b * 256 + t, F_IN);
    } else if (b < 320) {
        wsplit(W2, W2h, W2l, (b - 64) * 256 + t, HD);
    } else if (b < 576) {
        wsplit(W3, W3h, W3l, (b - 320) * 256 + t, HD);
    } else {
        int g = (b - 576) * 256 + t;
        if (g > N_GRAPHS) return;
        int lo = 0, hi = N_NODES;
        while (lo < hi) {
            int mid = (lo + hi) >> 1;
            if (node_graph[mid] < g) lo = mid + 1; else hi = mid;
        }
        gstart[g] = lo;
    }
}

// ---------------- split-f16 MFMA GEMM body: 64x128 tile, LDS-staged coalesced C writes ----------------
// ATERMS==3: A split hi+lo (ah*bh + ah*bl + alo*bh). ATERMS==2: A is f16-only (ah*bh + ah*bl).
// ctile padded to BN+4 (stride 264B = 66 dwords): consecutive rows offset 2 banks -> no 4-way
// conflict on the f16x8 epilogue reads (was 3.2M SQ_LDS_BANK_CONFLICT unpadded).
template <int K, bool F32A, int ATERMS>
__device__ __forceinline__ void gemm_body(int bx, int by,
                                          const void* __restrict__ Aptr,
                                          const _Float16* __restrict__ Alo_p,
                                          const _Float16* __restrict__ Bt_hi,
                                          const _Float16* __restrict__ Bt_lo,
                                          const float* __restrict__ al,
                                          const float* __restrict__ ar,
                                          _Float16* __restrict__ Chi,
                                          float* __restrict__ el,
                                          float* __restrict__ er, int M) {
    const int BM = 64, BN = 128, LDP = 40, LDC = BN + 4;
    __shared__ union U {
        struct {
            _Float16 Ash[BM][LDP];
            _Float16 Asl[BM][LDP];
            _Float16 Bsh[BN][LDP];
            _Float16 Bsl[BN][LDP];
        } s;
        _Float16 ctile[BM][LDC];
    } u;
    __shared__ float pl[4][64];
    __shared__ float pr[4][64];
    _Float16 (&Ash)[BM][LDP] = u.s.Ash;
    _Float16 (&Asl)[BM][LDP] = u.s.Asl;
    _Float16 (&Bsh)[BN][LDP] = u.s.Bsh;
    _Float16 (&Bsl)[BN][LDP] = u.s.Bsl;

    int tid = threadIdx.x;
    int w = tid >> 6, lane = tid & 63;
    int q = lane >> 4, l16 = lane & 15;
    int row0 = by * BM, col0 = bx * BN;
    f32x4 acc[4][2] = {};

    int ar_ = tid >> 2, ao = (tid & 3) * 8;
    f16x8 rAh, rAl, rBh[2], rBl[2];

    auto load_tile = [&](int k0) {
        int gr = row0 + ar_;
        if constexpr (F32A) {
            const float* A32 = (const float*)Aptr;
            float vv[8] = {};
            if (gr < M) {
                float4 va = *(const float4*)(A32 + (size_t)gr * K + k0 + ao);
                float4 vb = *(const float4*)(A32 + (size_t)gr * K + k0 + ao + 4);
                vv[0] = va.x; vv[1] = va.y; vv[2] = va.z; vv[3] = va.w;
                vv[4] = vb.x; vv[5] = vb.y; vv[6] = vb.z; vv[7] = vb.w;
            }
            f16x8 h, l;
#pragma unroll
            for (int i = 0; i < 8; i++) {
                h[i] = (_Float16)vv[i];
                l[i] = (_Float16)(vv[i] - (float)h[i]);
            }
            rAh = h; rAl = l;
        } else {
            const _Float16* Ahi = (const _Float16*)Aptr;
            f16x8 vh = {};
            if (gr < M) {
                vh = *(const f16x8*)(Ahi + (size_t)gr * K + k0 + ao);
                if constexpr (ATERMS == 3) rAl = *(const f16x8*)(Alo_p + (size_t)gr * K + k0 + ao);
            } else if constexpr (ATERMS == 3) {
                rAl = f16x8{};
            }
            rAh = vh;
        }
#pragma unroll
        for (int c = 0; c < 2; c++) {
            int cc = tid + c * 256;
            int br = cc >> 2, bo = (cc & 3) * 8;
            int gb = col0 + br;
            rBh[c] = *(const f16x8*)(Bt_hi + (size_t)gb * K + k0 + bo);
            rBl[c] = *(const f16x8*)(Bt_lo + (size_t)gb * K + k0 + bo);
        }
    };
    auto store_tile = [&]() {
        *(f16x8*)&Ash[ar_][ao] = rAh;
        if constexpr (ATERMS == 3) *(f16x8*)&Asl[ar_][ao] = rAl;
#pragma unroll
        for (int c = 0; c < 2; c++) {
            int cc = tid + c * 256;
            int br = cc >> 2, bo = (cc & 3) * 8;
            *(f16x8*)&Bsh[br][bo] = rBh[c];
            *(f16x8*)&Bsl[br][bo] = rBl[c];
        }
    };

    load_tile(0);
    store_tile();
    __syncthreads();

    for (int k0 = 0; k0 < K; k0 += 32) {
        bool more = (k0 + 32) < K;
        if (more) load_tile(k0 + 32);

        f16x8 ah[4], alo2[4], bh[2], bl[2];
#pragma unroll
        for (int mf = 0; mf < 4; mf++) {
            int m = mf * 16 + l16;
            ah[mf] = *(const f16x8*)&Ash[m][q * 8];
            if constexpr (ATERMS == 3) alo2[mf] = *(const f16x8*)&Asl[m][q * 8];
        }
#pragma unroll
        for (int nf = 0; nf < 2; nf++) {
            int n = w * 32 + nf * 16 + l16;
            bh[nf] = *(const f16x8*)&Bsh[n][q * 8];
            bl[nf] = *(const f16x8*)&Bsl[n][q * 8];
        }
#pragma unroll
        for (int mf = 0; mf < 4; mf++)
#pragma unroll
            for (int nf = 0; nf < 2; nf++) {
                acc[mf][nf] = __builtin_amdgcn_mfma_f32_16x16x32_f16(ah[mf], bh[nf], acc[mf][nf], 0, 0, 0);
                acc[mf][nf] = __builtin_amdgcn_mfma_f32_16x16x32_f16(ah[mf], bl[nf], acc[mf][nf], 0, 0, 0);
                if constexpr (ATERMS == 3)
                    acc[mf][nf] = __builtin_amdgcn_mfma_f32_16x16x32_f16(alo2[mf], bh[nf], acc[mf][nf], 0, 0, 0);
            }
        if (more) {
            __syncthreads();
            store_tile();
            __syncthreads();
        }
    }

    __syncthreads();

    const int hh = (col0 >> 6) + (w >> 1);
    float alv[2], arv[2];
#pragma unroll
    for (int nf = 0; nf < 2; nf++) {
        int d = (w & 1) * 32 + nf * 16 + l16;
        alv[nf] = al[hh * 64 + d];
        arv[nf] = ar[hh * 64 + d];
    }
#pragma unroll
    for (int mf = 0; mf < 4; mf++) {
#pragma unroll
        for (int i = 0; i < 4; i++) {
            int rl = mf * 16 + q * 4 + i;
            float e_l = 0.f, e_r = 0.f;
#pragma unroll
            for (int nf = 0; nf < 2; nf++) {
                float v = acc[mf][nf][i];
                u.ctile[rl][w * 32 + nf * 16 + l16] = (_Float16)v;
                e_l = fmaf(v, alv[nf], e_l);
                e_r = fmaf(v, arv[nf], e_r);
            }
#pragma unroll
            for (int off = 1; off < 16; off <<= 1) {
                e_l += __shfl_xor(e_l, off, 64);
                e_r += __shfl_xor(e_r, off, 64);
            }
            if (l16 == 0) {
                pl[w][rl] = e_l;
                pr[w][rl] = e_r;
            }
        }
    }
    __syncthreads();
#pragma unroll
    for (int j = 0; j < 4; j++) {
        int c = tid + j * 256;
        int rr2 = c >> 4, co = (c & 15) * 8;
        int gr = row0 + rr2;
        if (gr < M)
            *(f16x8*)(Chi + (size_t)gr * HD + col0 + co) = *(const f16x8*)&u.ctile[rr2][co];
    }
    int h2 = (tid >> 6) & 1, rr = tid & 63;
    int grow = row0 + rr;
    if (grow < M) {
        if (tid < 128) el[(size_t)grow * 4 + (col0 >> 6) + h2] = pl[2 * h2][rr] + pl[2 * h2 + 1][rr];
        else           er[(size_t)grow * 4 + (col0 >> 6) + h2] = pr[2 * h2][rr] + pr[2 * h2 + 1][rr];
    }
}

// standalone GEMM wrapper (layers 2/3)
template <int K, bool F32A, int ATERMS>
__global__ __launch_bounds__(256) void gemm_k(const void* __restrict__ Aptr,
                                              const _Float16* __restrict__ Alo_p,
                                              const _Float16* __restrict__ Bt_hi,
                                              const _Float16* __restrict__ Bt_lo,
                                              const float* __restrict__ al,
                                              const float* __restrict__ ar,
                                              _Float16* __restrict__ Chi,
                                              float* __restrict__ el,
                                              float* __restrict__ er, int M) {
    gemm_body<K, F32A, ATERMS>(blockIdx.x, blockIdx.y, Aptr, Alo_p, Bt_hi, Bt_lo, al, ar, Chi, el, er, M);
}

// ---------------- layer-1 GEMM with embedded edge-scatter prologue ----------------
__global__ __launch_bounds__(256) void gemm1s_k(const int* __restrict__ src,
                                                const int* __restrict__ dst,
                                                int* __restrict__ cursor,
                                                int* __restrict__ csr_src,
                                                const float* __restrict__ feats_node,
                                                const _Float16* __restrict__ W1h,
                                                const _Float16* __restrict__ W1l,
                                                const float* __restrict__ al1,
                                                const float* __restrict__ ar1,
                                                _Float16* __restrict__ hhi,
                                                float* __restrict__ el,
                                                float* __restrict__ er) {
    int lid = blockIdx.x * 256 + threadIdx.x;  // < 800256
    {
        int j = lid;  // always < N_EDGES
        int r = atomicAdd(&cursor[dst[j]], 1);
        r = r < N_EDGES ? r : N_EDGES - 1;  // replay-safety clamp (no-op in clean run)
        csr_src[r] = src[j];
        int j2 = lid + 800256;
        if (j2 < N_EDGES) {
            int r2 = atomicAdd(&cursor[dst[j2]], 1);
            r2 = r2 < N_EDGES ? r2 : N_EDGES - 1;
            csr_src[r2] = src[j2];
        }
    }
    gemm_body<F_IN, true, 3>(blockIdx.x & 1, blockIdx.x >> 1, (const void*)feats_node, nullptr,
                             W1h, W1l, al1, ar1, hhi, el, er, N_NODES);
}

// ---------------- GAT aggregation (R13: in-wave bitonic src sort for L2 locality) ----------------
// Fast path sorts the <=64 neighbor ids ascending (21-step shfl_xor bitonic network) before any
// gather: co-resident waves then sweep the source space front-to-back together, clustering L2
// accesses into a moving window instead of 51MB-random. Softmax/sums are order-independent.
// Aggregation lane layout:
//   eo = lane>>5  : which edge of a pair this half-wave handles
//   fl = lane&31  : feature-lane, covers features [fl*8, fl*8+8)  (head = fl>>3)
template <int OUT>
__global__ __launch_bounds__(256) void gat_aggregate_k(const _Float16* __restrict__ hb,
                                                       const float* __restrict__ el,
                                                       const float* __restrict__ er,
                                                       const int* __restrict__ csr_src,
                                                       const int* __restrict__ row_ptr,
                                                       const float* __restrict__ bias,
                                                       _Float16* __restrict__ xhi,
                                                       const float* __restrict__ sw,
                                                       const float* __restrict__ sb,
                                                       float* __restrict__ wsc) {
    __shared__ float wlds[4][64][4];
    __shared__ int snlds[4][64];
    int wv = threadIdx.x >> 6;
    int lane = threadIdx.x & 63;
    int v = blockIdx.x * 4 + wv;
    bool valid = v < N_NODES;
    int vc = valid ? v : 0;
    int rs = row_ptr[vc];
    int deg = valid ? row_ptr[vc + 1] - rs : 0;
    float4 erv = make_float4(0.f, 0.f, 0.f, 0.f);
    if (valid) erv = *(const float4*)(er + (size_t)vc * 4);

    const int eo = lane >> 5;
    const int fl = lane & 31;
    const int headf = fl >> 3;

    float a[8] = {};
    float dw = 0.f;          // per-(parity,head) partial denominator
    float m_h = 0.f, er_h = 0.f;

    if (deg <= 64) {
        int my_sn = 0x7fffffff;
        if (lane < deg) my_sn = csr_src[rs + lane];
        // in-register bitonic ascending sort across 64 lanes (INT_MAX pads sink to the end)
#pragma unroll
        for (int k = 2; k <= 64; k <<= 1) {
#pragma unroll
            for (int j = k >> 1; j >= 1; j >>= 1) {
                int pv = __shfl_xor(my_sn, j, 64);
                bool keepMin = ((lane & j) == 0) == ((lane & k) == 0);
                int mn = my_sn < pv ? my_sn : pv;
                int mx = my_sn > pv ? my_sn : pv;
                my_sn = keepMin ? mn : mx;
            }
        }
        int P = (deg + 1) >> 1;  // pairs; this lane handles edge 2p+eo
        f16x8 hv[8];
        // prologue A: first 4 pairs via shfl (before LDS weights exist)
        int pA = P < 4 ? P : 4;
#pragma unroll
        for (int u = 0; u < 4; u++) {
            if (u < pA) {
                int idx = 2 * u + eo;
                int cidx = idx < deg ? idx : deg - 1;
                int snb = __shfl(my_sn, cidx, 64);
                hv[u] = *(const f16x8*)(hb + (size_t)snb * HD + fl * 8);
            }
        }
        float e0 = -1e30f, e1 = -1e30f, e2 = -1e30f, e3 = -1e30f;
        if (lane < deg) {
            float4 elv = *(const float4*)(el + (size_t)my_sn * 4);
            float t0 = elv.x + erv.x, t1 = elv.y + erv.y, t2 = elv.z + erv.z, t3 = elv.w + erv.w;
            e0 = t0 > 0.f ? t0 : 0.2f * t0;
            e1 = t1 > 0.f ? t1 : 0.2f * t1;
            e2 = t2 > 0.f ? t2 : 0.2f * t2;
            e3 = t3 > 0.f ? t3 : 0.2f * t3;
        }
        // per-head max reduce (stability); denominator accumulated in the agg loop
        float m0 = e0, m1 = e1, m2 = e2, m3 = e3;
        for (int off = 1; off < deg; off <<= 1) {
            m0 = fmaxf(m0, __shfl_xor(m0, off, 64));
            m1 = fmaxf(m1, __shfl_xor(m1, off, 64));
            m2 = fmaxf(m2, __shfl_xor(m2, off, 64));
            m3 = fmaxf(m3, __shfl_xor(m3, off, 64));
        }
        if (lane < deg) {
            wlds[wv][lane][0] = __expf(e0 - m0);
            wlds[wv][lane][1] = __expf(e1 - m1);
            wlds[wv][lane][2] = __expf(e2 - m2);
            wlds[wv][lane][3] = __expf(e3 - m3);
            snlds[wv][lane] = my_sn;
        }
        // no barrier: wave-private LDS slice

        // prologue B: pairs 4..7 from snlds
        int pB = P < 8 ? P : 8;
#pragma unroll
        for (int u = 4; u < 8; u++) {
            if (u < pB) {
                int idx = 2 * u + eo;
                int cidx = idx < deg ? idx : deg - 1;
                hv[u] = *(const f16x8*)(hb + (size_t)snlds[wv][cidx] * HD + fl * 8);
            }
        }
        // main ring: consume pair p (slot j=p&7), immediately reissue slot for pair p+8
        for (int pb = 0; pb < P; pb += 8) {
#pragma unroll
            for (int j = 0; j < 8; j++) {
                int p = pb + j;
                if (p >= P) break;  // P is wave-uniform
                int idx = 2 * p + eo;
                float w = (idx < deg) ? wlds[wv][idx][headf] : 0.f;
                dw += w;
                f16x8 h = hv[j];
#pragma unroll
                for (int i = 0; i < 8; i++) a[i] = fmaf(w, (float)h[i], a[i]);
                int pn = p + 8;
                if (pn < P) {
                    int idx2 = 2 * pn + eo;
                    int cidx2 = idx2 < deg ? idx2 : deg - 1;
                    hv[j] = *(const f16x8*)(hb + (size_t)snlds[wv][cidx2] * HD + fl * 8);
                }
            }
        }
    } else {
        // rare path (deg > 64): online softmax stats, then pair-edge aggregation with recomputed weights
        float m[4] = {-1e30f, -1e30f, -1e30f, -1e30f};
        float s[4] = {0.f, 0.f, 0.f, 0.f};
        for (int t = lane; t < deg; t += 64) {
            int sn = csr_src[rs + t];
            float4 elv = *(const float4*)(el + (size_t)sn * 4);
            float e[4];
            e[0] = elv.x + erv.x; e[1] = elv.y + erv.y; e[2] = elv.z + erv.z; e[3] = elv.w + erv.w;
#pragma unroll
            for (int hh = 0; hh < 4; hh++) {
                float ev = e[hh] > 0.f ? e[hh] : 0.2f * e[hh];
                float mn = fmaxf(m[hh], ev);
                s[hh] = s[hh] * __expf(m[hh] - mn) + __expf(ev - mn);
                m[hh] = mn;
            }
        }
#pragma unroll
        for (int off = 32; off >= 1; off >>= 1) {
#pragma unroll
            for (int hh = 0; hh < 4; hh++) {
                float mo = __shfl_xor(m[hh], off, 64);
                float so = __shfl_xor(s[hh], off, 64);
                float mn = fmaxf(m[hh], mo);
                s[hh] = s[hh] * __expf(m[hh] - mn) + so * __expf(mo - mn);
                m[hh] = mn;
            }
        }
        m_h = headf == 0 ? m[0] : headf == 1 ? m[1] : headf == 2 ? m[2] : m[3];
        float dh = headf == 0 ? s[0] : headf == 1 ? s[1] : headf == 2 ? s[2] : s[3];
        er_h = headf == 0 ? erv.x : headf == 1 ? erv.y : headf == 2 ? erv.z : erv.w;
        dw = (eo == 0) ? dh : 0.f;  // combine at epilogue reconstructs dh

        for (int t = 0; t < deg; t += 2) {
            int idx = t + eo;
            int cidx = idx < deg ? idx : idx - 1;
            int sn = csr_src[rs + cidx];
            float w = 0.f;
            if (idx < deg) {
                float e = el[(size_t)sn * 4 + headf] + er_h;
                e = e > 0.f ? e : 0.2f * e;
                w = __expf(e - m_h);
            }
            f16x8 hv = *(const f16x8*)(hb + (size_t)sn * HD + fl * 8);
#pragma unroll
            for (int i = 0; i < 8; i++) a[i] = fmaf(w, (float)hv[i], a[i]);
        }
    }

    // combine even/odd halves (lane <-> lane^32) and finish
#pragma unroll
    for (int i = 0; i < 8; i++) a[i] += __shfl_xor(a[i], 32, 64);
    dw += __shfl_xor(dw, 32, 64);
    float inv_den = 1.f / fmaxf(dw, 1e-9f);

    float4 bv0 = *(const float4*)(bias + fl * 8);
    float4 bv1 = *(const float4*)(bias + fl * 8 + 4);
    float o[8];
    o[0] = selu_f(fmaf(a[0], inv_den, bv0.x));
    o[1] = selu_f(fmaf(a[1], inv_den, bv0.y));
    o[2] = selu_f(fmaf(a[2], inv_den, bv0.z));
    o[3] = selu_f(fmaf(a[3], inv_den, bv0.w));
    o[4] = selu_f(fmaf(a[4], inv_den, bv1.x));
    o[5] = selu_f(fmaf(a[5], inv_den, bv1.y));
    o[6] = selu_f(fmaf(a[6], inv_den, bv1.z));
    o[7] = selu_f(fmaf(a[7], inv_den, bv1.w));

    if constexpr (OUT == 0) {
        // hi-only output (f16): eo==0 half stores the full row
        if (valid && eo == 0) {
            f16x8 oh;
#pragma unroll
            for (int i = 0; i < 8; i++) oh[i] = (_Float16)o[i];
            *(f16x8*)(xhi + (size_t)v * HD + fl * 8) = oh;
        }
    } else {
        // layer-3: f16 feature row (halves write + readout fetch) + fused sigmoid score
        float p;
        if (eo == 0) {
            if (valid) {
                f16x4 oh;
                oh.x = (_Float16)o[0]; oh.y = (_Float16)o[1];
                oh.z = (_Float16)o[2]; oh.w = (_Float16)o[3];
                *(f16x4*)(xhi + (size_t)v * HD + fl * 8) = oh;
            }
            float4 sv = *(const float4*)(sw + fl * 8);
            p = o[0] * sv.x + o[1] * sv.y + o[2] * sv.z + o[3] * sv.w;
        } else {
            if (valid) {
                f16x4 oh;
                oh.x = (_Float16)o[4]; oh.y = (_Float16)o[5];
                oh.z = (_Float16)o[6]; oh.w = (_Float16)o[7];
                *(f16x4*)(xhi + (size_t)v * HD + fl * 8 + 4) = oh;
            }
            float4 sv = *(const float4*)(sw + fl * 8 + 4);
            p = o[4] * sv.x + o[5] * sv.y + o[6] * sv.z + o[7] * sv.w;
        }
#pragma unroll
        for (int off = 1; off < 64; off <<= 1) p += __shfl_xor(p, off, 64);
        if (lane == 0 && valid) wsc[v] = 1.f / (1.f + __expf(-(p + sb[0])));
    }
}

// ---------------- readout: 4 chunk-partials per graph (deterministic, f16 x) ----------------
__global__ __launch_bounds__(256) void readout_part_k(const _Float16* __restrict__ x,
                                                      const float* __restrict__ wsc,
                                                      const int* __restrict__ gstart,
                                                      float* __restrict__ y0p) {
    int g = blockIdx.x >> 2, c = blockIdx.x & 3;
    int f = threadIdx.x;
    int s0 = gstart[g], e0 = gstart[g + 1];
    int len = e0 - s0;
    int cs = s0 + (len * c) / 4, ce = s0 + (len * (c + 1)) / 4;
    float num = 0.f, den = 0.f;
#pragma unroll 4
    for (int n = cs; n < ce; n++) {
        float wn = wsc[n];
        num = fmaf(wn, (float)x[(size_t)n * HD + f], num);
        den += wn;
    }
    float* dst = y0p + (size_t)(g * 4 + c) * 257;
    dst[f] = num;
    if (f == 0) dst[256] = den;
}

__global__ __launch_bounds__(128) void mlp_k(const float* __restrict__ y0p,
                                             const float* __restrict__ fg,
                                             const float* __restrict__ lw1, const float* __restrict__ lb1,
                                             const float* __restrict__ lw2, const float* __restrict__ lb2,
                                             const float* __restrict__ lw3, const float* __restrict__ lb3,
                                             float* __restrict__ out) {
    __shared__ float y0s[272];
    __shared__ float y1s[128];
    int g = blockIdx.x, t = threadIdx.x;
    const float* p0 = y0p + (size_t)(g * 4 + 0) * 257;
    const float* p1 = y0p + (size_t)(g * 4 + 1) * 257;
    const float* p2 = y0p + (size_t)(g * 4 + 2) * 257;
    const float* p3 = y0p + (size_t)(g * 4 + 3) * 257;
    float den = p0[256] + p1[256] + p2[256] + p3[256];
    float invden = 1.f / fmaxf(den, 1e-9f);
    for (int i = t; i < 256; i += 128)
        y0s[i] = (p0[i] + p1[i] + p2[i] + p3[i]) * invden;
    if (t < EXTRA) y0s[256 + t] = fg[g * EXTRA + t];
    __syncthreads();
    float acc = lb1[t];
    for (int k = 0; k < 272; k++) acc = fmaf(y0s[k], lw1[k * 128 + t], acc);
    y1s[t] = selu_f(acc);
    __syncthreads();
    if (t < 64) {
        float a2 = lb2[t];
        for (int k = 0; k < 128; k++) a2 = fmaf(y1s[k], lw2[k * 64 + t], a2);
        float v2 = selu_f(a2);
        float p = v2 * lw3[t];
#pragma unroll
        for (int off = 1; off < 64; off <<= 1) p += __shfl_xor(p, off, 64);
        if (t == 0) out[g] = p + lb3[0];
    }
}

extern "C" void kernel_launch(void* const* d_in, const int* in_sizes, int n_in,
                              void* d_out, int out_size, void* d_ws, size_t ws_size,
                              hipStream_t stream) {
    const int* src = (const int*)d_in[0];
    const int* dst = (const int*)d_in[1];
    const int* node_graph = (const int*)d_in[2];
    const float* feats_node = (const float*)d_in[3];
    const float* feats_graph = (const float*)d_in[4];
    const float* W1 = (const float*)d_in[5];
    const float* al1 = (const float*)d_in[6];
    const float* ar1 = (const float*)d_in[7];
    const float* bg1 = (const float*)d_in[8];
    const float* W2 = (const float*)d_in[9];
    const float* al2 = (const float*)d_in[10];
    const float* ar2 = (const float*)d_in[11];
    const float* bg2 = (const float*)d_in[12];
    const float* W3 = (const float*)d_in[13];
    const float* al3 = (const float*)d_in[14];
    const float* ar3 = (const float*)d_in[15];
    const float* bg3 = (const float*)d_in[16];
    const float* sw = (const float*)d_in[17];
    const float* sb = (const float*)d_in[18];
    const float* lw1 = (const float*)d_in[19];
    const float* lb1 = (const float*)d_in[20];
    const float* lw2 = (const float*)d_in[21];
    const float* lb2 = (const float*)d_in[22];
    const float* lw3 = (const float*)d_in[23];
    const float* lb3 = (const float*)d_in[24];
    float* out = (float*)d_out;

    char* ws = (char*)d_ws;
    size_t off = 0;
    auto alloc = [&](size_t bytes) -> char* {
        char* p = ws + off;
        off += (bytes + 255) & ~(size_t)255;
        return p;
    };
    _Float16* xhi = (_Float16*)alloc((size_t)N_NODES * HD * 2);
    _Float16* hhi = (_Float16*)alloc((size_t)N_NODES * HD * 2);
    _Float16* W1hi = (_Float16*)alloc((size_t)F_IN * HD * 2);
    _Float16* W1lo = (_Float16*)alloc((size_t)F_IN * HD * 2);
    _Float16* W2hi = (_Float16*)alloc((size_t)HD * HD * 2);
    _Float16* W2lo = (_Float16*)alloc((size_t)HD * HD * 2);
    _Float16* W3hi = (_Float16*)alloc((size_t)HD * HD * 2);
    _Float16* W3lo = (_Float16*)alloc((size_t)HD * HD * 2);
    float* el = (float*)alloc((size_t)N_NODES * 4 * 4);
    float* er = (float*)alloc((size_t)N_NODES * 4 * 4);
    float* wsc = (float*)alloc((size_t)N_NODES * 4);
    float* y0p = (float*)alloc((size_t)N_GRAPHS * 4 * 257 * 4);
    int* hist = (int*)alloc((size_t)N_NODES * 4);
    int* row_ptr = (int*)alloc((size_t)(N_NODES + 1) * 4);
    int* cursor = (int*)alloc((size_t)N_NODES * 4);
    int* csr_src = (int*)alloc((size_t)N_EDGES * 4);
    int* gstart = (int*)alloc((size_t)(N_GRAPHS + 1) * 4);
    int* bsums = (int*)alloc(256 * 4);
    (void)ws_size; (void)in_sizes; (void)n_in; (void)out_size;

    hipMemsetAsync(hist, 0, (size_t)N_NODES * 4, stream);

    // fused: hist (random atomics) || weight splits + graph bounds
    histprep_k<<<EDGE_BLOCKS + 579, 256, 0, stream>>>(dst, hist, W1, W2, W3,
                                                      W1hi, W1lo, W2hi, W2lo, W3hi, W3lo,
                                                      node_graph, gstart);
    int nb = (N_NODES + SCAN_BLOCK - 1) / SCAN_BLOCK;  // 196 <= 256
    scan1_k<<<nb, SCAN_BLOCK, 0, stream>>>(hist, row_ptr, bsums);
    scan23_k<<<(N_NODES + 255) / 256, 256, 0, stream>>>(row_ptr, bsums, cursor, nb);

    dim3 ggrid(HD / 128, (N_NODES + 63) / 64);
    int g1blocks = (HD / 128) * ((N_NODES + 63) / 64);  // 3126
    int nwb = (N_NODES + 3) / 4;

    // layer-1 GEMM with embedded edge-scatter prologue (2 edges/thread)
    gemm1s_k<<<g1blocks, 256, 0, stream>>>(src, dst, cursor, csr_src,
                                           feats_node, W1hi, W1lo, al1, ar1, hhi, el, er);
    gat_aggregate_k<0><<<nwb, 256, 0, stream>>>(hhi, el, er, csr_src, row_ptr, bg1, xhi, nullptr, nullptr, nullptr);
    // layer 2 (A = f16 hi-only, 2-term)
    gemm_k<HD, false, 2><<<ggrid, 256, 0, stream>>>((const void*)xhi, nullptr, W2hi, W2lo, al2, ar2, hhi, el, er, N_NODES);
    gat_aggregate_k<0><<<nwb, 256, 0, stream>>>(hhi, el, er, csr_src, row_ptr, bg2, xhi, nullptr, nullptr, nullptr);
    // layer 3 (A = f16 hi-only, 2-term; f16 out + fused sigmoid score)
    gemm_k<HD, false, 2><<<ggrid, 256, 0, stream>>>((const void*)xhi, nullptr, W3hi, W3lo, al3, ar3, hhi, el, er, N_NODES);
    gat_aggregate_k<1><<<nwb, 256, 0, stream>>>(hhi, el, er, csr_src, row_ptr, bg3, xhi, sw, sb, wsc);

    // readout (4 partials/graph, f16 x) + MLP
    readout_part_k<<<N_GRAPHS * 4, 256, 0, stream>>>(xhi, wsc, gstart, y0p);
    mlp_k<<<N_GRAPHS, 128, 0, stream>>>(y0p, feats_graph, lw1, lb1, lw2, lb2, lw3, lb3, out);
}

// Round 8
// 832.868 us; speedup vs baseline: 1.0258x; 1.0258x over previous
//
#include <hip/hip_runtime.h>

#define N_NODES 100000
#define N_EDGES 1600000
#define N_GRAPHS 512
#define F_IN 64
#define HD 256
#define EXTRA 16
#define SCAN_BLOCK 512
#define EDGE_BLOCKS 6250  // (N_EDGES+255)/256

typedef float f32x4 __attribute__((ext_vector_type(4)));
typedef _Float16 f16x4 __attribute__((ext_vector_type(4)));
typedef _Float16 f16x8 __attribute__((ext_vector_type(8)));

__device__ __forceinline__ float selu_f(float x) {
    const float a = 1.6732632423543772f, sc = 1.0507009873554805f;
    return x > 0.f ? sc * x : sc * a * (__expf(x) - 1.f);
}

// ---------------- CSR build ----------------
__global__ __launch_bounds__(SCAN_BLOCK) void scan1_k(const int* __restrict__ hist,
                                                      int* __restrict__ row_ptr,
                                                      int* __restrict__ bsums) {
    __shared__ int sm[SCAN_BLOCK];
    int t = threadIdx.x;
    int i = blockIdx.x * SCAN_BLOCK + t;
    int v = (i < N_NODES) ? hist[i] : 0;
    sm[t] = v;
    __syncthreads();
    for (int off = 1; off < SCAN_BLOCK; off <<= 1) {
        int add = (t >= off) ? sm[t - off] : 0;
        __syncthreads();
        sm[t] += add;
        __syncthreads();
    }
    if (i < N_NODES) row_ptr[i] = sm[t] - v;
    if (t == SCAN_BLOCK - 1) bsums[blockIdx.x] = sm[t];
}

// merged scan2+scan3: each block re-scans the (<=256) block sums in LDS,
// finalizes row_ptr AND initializes cursor = row_ptr.
__global__ __launch_bounds__(256) void scan23_k(int* __restrict__ row_ptr, const int* __restrict__ bsums,
                                                int* __restrict__ cursor, int nb) {
    __shared__ int bs[256];
    int t = threadIdx.x;
    bs[t] = (t < nb) ? bsums[t] : 0;
    __syncthreads();
    for (int off = 1; off < 256; off <<= 1) {
        int add = (t >= off) ? bs[t - off] : 0;
        __syncthreads();
        bs[t] += add;
        __syncthreads();
    }
    int i = blockIdx.x * 256 + t;
    if (i < N_NODES) {
        int b = i / SCAN_BLOCK;
        int p = b > 0 ? bs[b - 1] : 0;
        int r = row_ptr[i] + p;
        row_ptr[i] = r;
        cursor[i] = r;
    }
    if (i == 0) row_ptr[N_NODES] = N_EDGES;
}

// ---------------- fused: hist (random atomics, LDS-free) || weight splits + graph bounds ----------------
__device__ __forceinline__ void wsplit(const float* __restrict__ W, _Float16* __restrict__ Wh,
                                       _Float16* __restrict__ Wl, int idx, int K) {
    int n = idx / K, k = idx - n * K;
    float w = W[(size_t)k * HD + n];
    _Float16 hi = (_Float16)w;
    Wh[idx] = hi;
    Wl[idx] = (_Float16)(w - (float)hi);
}

__global__ __launch_bounds__(256) void histprep_k(const int* __restrict__ dst, int* __restrict__ hist,
                                                  const float* __restrict__ W1,
                                                  const float* __restrict__ W2,
                                                  const float* __restrict__ W3,
                                                  _Float16* __restrict__ W1h, _Float16* __restrict__ W1l,
                                                  _Float16* __restrict__ W2h, _Float16* __restrict__ W2l,
                                                  _Float16* __restrict__ W3h, _Float16* __restrict__ W3l,
                                                  const int* __restrict__ node_graph,
                                                  int* __restrict__ gstart) {
    int bid = blockIdx.x, t = threadIdx.x;
    if (bid < EDGE_BLOCKS) {
        int j = bid * 256 + t;
        if (j < N_EDGES) atomicAdd(&hist[dst[j]], 1);
        return;
    }
    int b = bid - EDGE_BLOCKS;
    if (b < 64) {
        wsplit(W1, W1h, W1l, b * 256 + t, F_IN);
    } else if (b < 320) {
        wsplit(W2, W2h, W2l, (b - 64) * 256 + t, HD);
    } else if (b < 576) {
        wsplit(W3, W3h, W3l, (b - 320) * 256 + t, HD);
    } else {
        int g = (b - 576) * 256 + t;
        if (g > N_GRAPHS) return;
        int lo = 0, hi = N_NODES;
        while (lo < hi) {
            int mid = (lo + hi) >> 1;
            if (node_graph[mid] < g) lo = mid + 1; else hi = mid;
        }
        gstart[g] = lo;
    }
}

// ---------------- split-f16 MFMA GEMM body: 64x128 tile, LDS-staged coalesced C writes ----------------
// ATERMS==3: A split hi+lo (ah*bh + ah*bl + alo*bh). ATERMS==2: A is f16-only (ah*bh + ah*bl).
// ctile padded to BN+4 (stride 264B): no 4-way bank conflict on f16x8 epilogue reads.
// NBUF==2 (2-term f16-A path, layers 2/3): double-buffered LDS staging -> ONE barrier per
// K-step instead of two (the drain-before-store barrier is the classic ~20% stall).
template <int K, bool F32A, int ATERMS>
__device__ __forceinline__ void gemm_body(int bx, int by,
                                          const void* __restrict__ Aptr,
                                          const _Float16* __restrict__ Alo_p,
                                          const _Float16* __restrict__ Bt_hi,
                                          const _Float16* __restrict__ Bt_lo,
                                          const float* __restrict__ al,
                                          const float* __restrict__ ar,
                                          _Float16* __restrict__ Chi,
                                          float* __restrict__ el,
                                          float* __restrict__ er, int M) {
    const int BM = 64, BN = 128, LDP = 40, LDC = BN + 4;
    constexpr int NBUF = (!F32A && ATERMS == 2) ? 2 : 1;
    constexpr int ASZ = BM * LDP * 2;            // bytes per A-hi stage
    constexpr int BSZ = BN * LDP * 2;            // bytes per B stage
    constexpr int STRIDE = ASZ + 2 * BSZ;        // one staging buffer (Ash+Bsh+Bsl)
    constexpr int STG = NBUF * STRIDE + (ATERMS == 3 ? ASZ : 0);  // + Asl (single-buf only)
    constexpr int CTB = BM * LDC * 2;
    __shared__ __align__(16) char smem[(STG > CTB ? STG : CTB)];
    __shared__ float pl[4][64];
    __shared__ float pr[4][64];

    auto Ash = [&](int b) -> _Float16 (*)[LDP] { return (_Float16 (*)[LDP])(smem + b * STRIDE); };
    auto Bsh = [&](int b) -> _Float16 (*)[LDP] { return (_Float16 (*)[LDP])(smem + b * STRIDE + ASZ); };
    auto Bsl = [&](int b) -> _Float16 (*)[LDP] { return (_Float16 (*)[LDP])(smem + b * STRIDE + ASZ + BSZ); };
    _Float16 (*Asl)[LDP] = (_Float16 (*)[LDP])(smem + NBUF * STRIDE);  // deref'd only when ATERMS==3
    _Float16 (*ctile)[LDC] = (_Float16 (*)[LDC])smem;

    int tid = threadIdx.x;
    int w = tid >> 6, lane = tid & 63;
    int q = lane >> 4, l16 = lane & 15;
    int row0 = by * BM, col0 = bx * BN;
    f32x4 acc[4][2] = {};

    int ar_ = tid >> 2, ao = (tid & 3) * 8;
    f16x8 rAh, rAl, rBh[2], rBl[2];

    auto load_tile = [&](int k0) {
        int gr = row0 + ar_;
        if constexpr (F32A) {
            const float* A32 = (const float*)Aptr;
            float vv[8] = {};
            if (gr < M) {
                float4 va = *(const float4*)(A32 + (size_t)gr * K + k0 + ao);
                float4 vb = *(const float4*)(A32 + (size_t)gr * K + k0 + ao + 4);
                vv[0] = va.x; vv[1] = va.y; vv[2] = va.z; vv[3] = va.w;
                vv[4] = vb.x; vv[5] = vb.y; vv[6] = vb.z; vv[7] = vb.w;
            }
            f16x8 h, l;
#pragma unroll
            for (int i = 0; i < 8; i++) {
                h[i] = (_Float16)vv[i];
                l[i] = (_Float16)(vv[i] - (float)h[i]);
            }
            rAh = h; rAl = l;
        } else {
            const _Float16* Ahi = (const _Float16*)Aptr;
            f16x8 vh = {};
            if (gr < M) {
                vh = *(const f16x8*)(Ahi + (size_t)gr * K + k0 + ao);
                if constexpr (ATERMS == 3) rAl = *(const f16x8*)(Alo_p + (size_t)gr * K + k0 + ao);
            } else if constexpr (ATERMS == 3) {
                rAl = f16x8{};
            }
            rAh = vh;
        }
#pragma unroll
        for (int c = 0; c < 2; c++) {
            int cc = tid + c * 256;
            int br = cc >> 2, bo = (cc & 3) * 8;
            int gb = col0 + br;
            rBh[c] = *(const f16x8*)(Bt_hi + (size_t)gb * K + k0 + bo);
            rBl[c] = *(const f16x8*)(Bt_lo + (size_t)gb * K + k0 + bo);
        }
    };
    auto store_tile = [&](int b) {
        *(f16x8*)&Ash(b)[ar_][ao] = rAh;
        if constexpr (ATERMS == 3) *(f16x8*)&Asl[ar_][ao] = rAl;
#pragma unroll
        for (int c = 0; c < 2; c++) {
            int cc = tid + c * 256;
            int br = cc >> 2, bo = (cc & 3) * 8;
            *(f16x8*)&Bsh(b)[br][bo] = rBh[c];
            *(f16x8*)&Bsl(b)[br][bo] = rBl[c];
        }
    };

    load_tile(0);
    store_tile(0);
    __syncthreads();

    int cur = 0;
    for (int k0 = 0; k0 < K; k0 += 32) {
        bool more = (k0 + 32) < K;
        if (more) load_tile(k0 + 32);

        f16x8 ah[4], alo2[4], bh[2], bl[2];
#pragma unroll
        for (int mf = 0; mf < 4; mf++) {
            int m = mf * 16 + l16;
            ah[mf] = *(const f16x8*)&Ash(cur)[m][q * 8];
            if constexpr (ATERMS == 3) alo2[mf] = *(const f16x8*)&Asl[m][q * 8];
        }
#pragma unroll
        for (int nf = 0; nf < 2; nf++) {
            int n = w * 32 + nf * 16 + l16;
            bh[nf] = *(const f16x8*)&Bsh(cur)[n][q * 8];
            bl[nf] = *(const f16x8*)&Bsl(cur)[n][q * 8];
        }
#pragma unroll
        for (int mf = 0; mf < 4; mf++)
#pragma unroll
            for (int nf = 0; nf < 2; nf++) {
                acc[mf][nf] = __builtin_amdgcn_mfma_f32_16x16x32_f16(ah[mf], bh[nf], acc[mf][nf], 0, 0, 0);
                acc[mf][nf] = __builtin_amdgcn_mfma_f32_16x16x32_f16(ah[mf], bl[nf], acc[mf][nf], 0, 0, 0);
                if constexpr (ATERMS == 3)
                    acc[mf][nf] = __builtin_amdgcn_mfma_f32_16x16x32_f16(alo2[mf], bh[nf], acc[mf][nf], 0, 0, 0);
            }
        if constexpr (NBUF == 2) {
            // store next tile into the other buffer; single barrier covers both
            // "stores visible" and "reads of cur drained before its next overwrite"
            if (more) store_tile(cur ^ 1);
            __syncthreads();
            cur ^= 1;
        } else {
            if (more) {
                __syncthreads();
                store_tile(0);
                __syncthreads();
            }
        }
    }

    __syncthreads();

    const int hh = (col0 >> 6) + (w >> 1);
    float alv[2], arv[2];
#pragma unroll
    for (int nf = 0; nf < 2; nf++) {
        int d = (w & 1) * 32 + nf * 16 + l16;
        alv[nf] = al[hh * 64 + d];
        arv[nf] = ar[hh * 64 + d];
    }
#pragma unroll
    for (int mf = 0; mf < 4; mf++) {
#pragma unroll
        for (int i = 0; i < 4; i++) {
            int rl = mf * 16 + q * 4 + i;
            float e_l = 0.f, e_r = 0.f;
#pragma unroll
            for (int nf = 0; nf < 2; nf++) {
                float v = acc[mf][nf][i];
                ctile[rl][w * 32 + nf * 16 + l16] = (_Float16)v;
                e_l = fmaf(v, alv[nf], e_l);
                e_r = fmaf(v, arv[nf], e_r);
            }
#pragma unroll
            for (int off = 1; off < 16; off <<= 1) {
                e_l += __shfl_xor(e_l, off, 64);
                e_r += __shfl_xor(e_r, off, 64);
            }
            if (l16 == 0) {
                pl[w][rl] = e_l;
                pr[w][rl] = e_r;
            }
        }
    }
    __syncthreads();
#pragma unroll
    for (int j = 0; j < 4; j++) {
        int c = tid + j * 256;
        int rr2 = c >> 4, co = (c & 15) * 8;
        int gr = row0 + rr2;
        if (gr < M)
            *(f16x8*)(Chi + (size_t)gr * HD + col0 + co) = *(const f16x8*)&ctile[rr2][co];
    }
    int h2 = (tid >> 6) & 1, rr = tid & 63;
    int grow = row0 + rr;
    if (grow < M) {
        if (tid < 128) el[(size_t)grow * 4 + (col0 >> 6) + h2] = pl[2 * h2][rr] + pl[2 * h2 + 1][rr];
        else           er[(size_t)grow * 4 + (col0 >> 6) + h2] = pr[2 * h2][rr] + pr[2 * h2 + 1][rr];
    }
}

// standalone GEMM wrapper (layers 2/3)
template <int K, bool F32A, int ATERMS>
__global__ __launch_bounds__(256) void gemm_k(const void* __restrict__ Aptr,
                                              const _Float16* __restrict__ Alo_p,
                                              const _Float16* __restrict__ Bt_hi,
                                              const _Float16* __restrict__ Bt_lo,
                                              const float* __restrict__ al,
                                              const float* __restrict__ ar,
                                              _Float16* __restrict__ Chi,
                                              float* __restrict__ el,
                                              float* __restrict__ er, int M) {
    gemm_body<K, F32A, ATERMS>(blockIdx.x, blockIdx.y, Aptr, Alo_p, Bt_hi, Bt_lo, al, ar, Chi, el, er, M);
}

// ---------------- layer-1 GEMM with embedded edge-scatter prologue ----------------
__global__ __launch_bounds__(256) void gemm1s_k(const int* __restrict__ src,
                                                const int* __restrict__ dst,
                                                int* __restrict__ cursor,
                                                int* __restrict__ csr_src,
                                                const float* __restrict__ feats_node,
                                                const _Float16* __restrict__ W1h,
                                                const _Float16* __restrict__ W1l,
                                                const float* __restrict__ al1,
                                                const float* __restrict__ ar1,
                                                _Float16* __restrict__ hhi,
                                                float* __restrict__ el,
                                                float* __restrict__ er) {
    int lid = blockIdx.x * 256 + threadIdx.x;  // < 800256
    {
        int j = lid;  // always < N_EDGES
        int r = atomicAdd(&cursor[dst[j]], 1);
        r = r < N_EDGES ? r : N_EDGES - 1;  // replay-safety clamp (no-op in clean run)
        csr_src[r] = src[j];
        int j2 = lid + 800256;
        if (j2 < N_EDGES) {
            int r2 = atomicAdd(&cursor[dst[j2]], 1);
            r2 = r2 < N_EDGES ? r2 : N_EDGES - 1;
            csr_src[r2] = src[j2];
        }
    }
    gemm_body<F_IN, true, 3>(blockIdx.x & 1, blockIdx.x >> 1, (const void*)feats_node, nullptr,
                             W1h, W1l, al1, ar1, hhi, el, er, N_NODES);
}

// ---------------- GAT aggregation (8-pair ring pipeline, f16 output both modes) ----------------
// Aggregation lane layout:
//   eo = lane>>5  : which edge of a pair this half-wave handles
//   fl = lane&31  : feature-lane, covers features [fl*8, fl*8+8)  (head = fl>>3)
template <int OUT>
__global__ __launch_bounds__(256) void gat_aggregate_k(const _Float16* __restrict__ hb,
                                                       const float* __restrict__ el,
                                                       const float* __restrict__ er,
                                                       const int* __restrict__ csr_src,
                                                       const int* __restrict__ row_ptr,
                                                       const float* __restrict__ bias,
                                                       _Float16* __restrict__ xhi,
                                                       const float* __restrict__ sw,
                                                       const float* __restrict__ sb,
                                                       float* __restrict__ wsc) {
    __shared__ float wlds[4][64][4];
    __shared__ int snlds[4][64];
    int wv = threadIdx.x >> 6;
    int lane = threadIdx.x & 63;
    int v = blockIdx.x * 4 + wv;
    bool valid = v < N_NODES;
    int vc = valid ? v : 0;
    int rs = row_ptr[vc];
    int deg = valid ? row_ptr[vc + 1] - rs : 0;
    float4 erv = make_float4(0.f, 0.f, 0.f, 0.f);
    if (valid) erv = *(const float4*)(er + (size_t)vc * 4);

    const int eo = lane >> 5;
    const int fl = lane & 31;
    const int headf = fl >> 3;

    float a[8] = {};
    float dw = 0.f;          // per-(parity,head) partial denominator
    float m_h = 0.f, er_h = 0.f;

    if (deg <= 64) {
        float e0 = -1e30f, e1 = -1e30f, e2 = -1e30f, e3 = -1e30f;
        int my_sn = 0;
        if (lane < deg) {
            my_sn = csr_src[rs + lane];
            float4 elv = *(const float4*)(el + (size_t)my_sn * 4);
            float t0 = elv.x + erv.x, t1 = elv.y + erv.y, t2 = elv.z + erv.z, t3 = elv.w + erv.w;
            e0 = t0 > 0.f ? t0 : 0.2f * t0;
            e1 = t1 > 0.f ? t1 : 0.2f * t1;
            e2 = t2 > 0.f ? t2 : 0.2f * t2;
            e3 = t3 > 0.f ? t3 : 0.2f * t3;
        }
        int P = (deg + 1) >> 1;  // pairs; this lane handles edge 2p+eo
        f16x8 hv[8];
        // prologue A: first 4 pairs via shfl (before LDS weights exist)
        int pA = P < 4 ? P : 4;
#pragma unroll
        for (int u = 0; u < 4; u++) {
            if (u < pA) {
                int idx = 2 * u + eo;
                int cidx = idx < deg ? idx : deg - 1;
                int snb = __shfl(my_sn, cidx, 64);
                hv[u] = *(const f16x8*)(hb + (size_t)snb * HD + fl * 8);
            }
        }
        // per-head max reduce (stability); denominator accumulated in the agg loop
        float m0 = e0, m1 = e1, m2 = e2, m3 = e3;
        for (int off = 1; off < deg; off <<= 1) {
            m0 = fmaxf(m0, __shfl_xor(m0, off, 64));
            m1 = fmaxf(m1, __shfl_xor(m1, off, 64));
            m2 = fmaxf(m2, __shfl_xor(m2, off, 64));
            m3 = fmaxf(m3, __shfl_xor(m3, off, 64));
        }
        if (lane < deg) {
            wlds[wv][lane][0] = __expf(e0 - m0);
            wlds[wv][lane][1] = __expf(e1 - m1);
            wlds[wv][lane][2] = __expf(e2 - m2);
            wlds[wv][lane][3] = __expf(e3 - m3);
            snlds[wv][lane] = my_sn;
        }
        // no barrier: wave-private LDS slice

        // prologue B: pairs 4..7 from snlds
        int pB = P < 8 ? P : 8;
#pragma unroll
        for (int u = 4; u < 8; u++) {
            if (u < pB) {
                int idx = 2 * u + eo;
                int cidx = idx < deg ? idx : deg - 1;
                hv[u] = *(const f16x8*)(hb + (size_t)snlds[wv][cidx] * HD + fl * 8);
            }
        }
        // main ring: consume pair p (slot j=p&7), immediately reissue slot for pair p+8
        for (int pb = 0; pb < P; pb += 8) {
#pragma unroll
            for (int j = 0; j < 8; j++) {
                int p = pb + j;
                if (p >= P) break;  // P is wave-uniform
                int idx = 2 * p + eo;
                float w = (idx < deg) ? wlds[wv][idx][headf] : 0.f;
                dw += w;
                f16x8 h = hv[j];
#pragma unroll
                for (int i = 0; i < 8; i++) a[i] = fmaf(w, (float)h[i], a[i]);
                int pn = p + 8;
                if (pn < P) {
                    int idx2 = 2 * pn + eo;
                    int cidx2 = idx2 < deg ? idx2 : deg - 1;
                    hv[j] = *(const f16x8*)(hb + (size_t)snlds[wv][cidx2] * HD + fl * 8);
                }
            }
        }
    } else {
        // rare path (deg > 64): online softmax stats, then pair-edge aggregation with recomputed weights
        float m[4] = {-1e30f, -1e30f, -1e30f, -1e30f};
        float s[4] = {0.f, 0.f, 0.f, 0.f};
        for (int t = lane; t < deg; t += 64) {
            int sn = csr_src[rs + t];
            float4 elv = *(const float4*)(el + (size_t)sn * 4);
            float e[4];
            e[0] = elv.x + erv.x; e[1] = elv.y + erv.y; e[2] = elv.z + erv.z; e[3] = elv.w + erv.w;
#pragma unroll
            for (int hh = 0; hh < 4; hh++) {
                float ev = e[hh] > 0.f ? e[hh] : 0.2f * e[hh];
                float mn = fmaxf(m[hh], ev);
                s[hh] = s[hh] * __expf(m[hh] - mn) + __expf(ev - mn);
                m[hh] = mn;
            }
        }
#pragma unroll
        for (int off = 32; off >= 1; off >>= 1) {
#pragma unroll
            for (int hh = 0; hh < 4; hh++) {
                float mo = __shfl_xor(m[hh], off, 64);
                float so = __shfl_xor(s[hh], off, 64);
                float mn = fmaxf(m[hh], mo);
                s[hh] = s[hh] * __expf(m[hh] - mn) + so * __expf(mo - mn);
                m[hh] = mn;
            }
        }
        m_h = headf == 0 ? m[0] : headf == 1 ? m[1] : headf == 2 ? m[2] : m[3];
        float dh = headf == 0 ? s[0] : headf == 1 ? s[1] : headf == 2 ? s[2] : s[3];
        er_h = headf == 0 ? erv.x : headf == 1 ? erv.y : headf == 2 ? erv.z : erv.w;
        dw = (eo == 0) ? dh : 0.f;  // combine at epilogue reconstructs dh

        for (int t = 0; t < deg; t += 2) {
            int idx = t + eo;
            int cidx = idx < deg ? idx : idx - 1;
            int sn = csr_src[rs + cidx];
            float w = 0.f;
            if (idx < deg) {
                float e = el[(size_t)sn * 4 + headf] + er_h;
                e = e > 0.f ? e : 0.2f * e;
                w = __expf(e - m_h);
            }
            f16x8 hv = *(const f16x8*)(hb + (size_t)sn * HD + fl * 8);
#pragma unroll
            for (int i = 0; i < 8; i++) a[i] = fmaf(w, (float)hv[i], a[i]);
        }
    }

    // combine even/odd halves (lane <-> lane^32) and finish
#pragma unroll
    for (int i = 0; i < 8; i++) a[i] += __shfl_xor(a[i], 32, 64);
    dw += __shfl_xor(dw, 32, 64);
    float inv_den = 1.f / fmaxf(dw, 1e-9f);

    float4 bv0 = *(const float4*)(bias + fl * 8);
    float4 bv1 = *(const float4*)(bias + fl * 8 + 4);
    float o[8];
    o[0] = selu_f(fmaf(a[0], inv_den, bv0.x));
    o[1] = selu_f(fmaf(a[1], inv_den, bv0.y));
    o[2] = selu_f(fmaf(a[2], inv_den, bv0.z));
    o[3] = selu_f(fmaf(a[3], inv_den, bv0.w));
    o[4] = selu_f(fmaf(a[4], inv_den, bv1.x));
    o[5] = selu_f(fmaf(a[5], inv_den, bv1.y));
    o[6] = selu_f(fmaf(a[6], inv_den, bv1.z));
    o[7] = selu_f(fmaf(a[7], inv_den, bv1.w));

    if constexpr (OUT == 0) {
        // hi-only output (f16): eo==0 half stores the full row
        if (valid && eo == 0) {
            f16x8 oh;
#pragma unroll
            for (int i = 0; i < 8; i++) oh[i] = (_Float16)o[i];
            *(f16x8*)(xhi + (size_t)v * HD + fl * 8) = oh;
        }
    } else {
        // layer-3: f16 feature row (halves write + readout fetch) + fused sigmoid score
        float p;
        if (eo == 0) {
            if (valid) {
                f16x4 oh;
                oh.x = (_Float16)o[0]; oh.y = (_Float16)o[1];
                oh.z = (_Float16)o[2]; oh.w = (_Float16)o[3];
                *(f16x4*)(xhi + (size_t)v * HD + fl * 8) = oh;
            }
            float4 sv = *(const float4*)(sw + fl * 8);
            p = o[0] * sv.x + o[1] * sv.y + o[2] * sv.z + o[3] * sv.w;
        } else {
            if (valid) {
                f16x4 oh;
                oh.x = (_Float16)o[4]; oh.y = (_Float16)o[5];
                oh.z = (_Float16)o[6]; oh.w = (_Float16)o[7];
                *(f16x4*)(xhi + (size_t)v * HD + fl * 8 + 4) = oh;
            }
            float4 sv = *(const float4*)(sw + fl * 8 + 4);
            p = o[4] * sv.x + o[5] * sv.y + o[6] * sv.z + o[7] * sv.w;
        }
#pragma unroll
        for (int off = 1; off < 64; off <<= 1) p += __shfl_xor(p, off, 64);
        if (lane == 0 && valid) wsc[v] = 1.f / (1.f + __expf(-(p + sb[0])));
    }
}

// ---------------- readout: 4 chunk-partials per graph (deterministic, f16 x) ----------------
__global__ __launch_bounds__(256) void readout_part_k(const _Float16* __restrict__ x,
                                                      const float* __restrict__ wsc,
                                                      const int* __restrict__ gstart,
                                                      float* __restrict__ y0p) {
    int g = blockIdx.x >> 2, c = blockIdx.x & 3;
    int f = threadIdx.x;
    int s0 = gstart[g], e0 = gstart[g + 1];
    int len = e0 - s0;
    int cs = s0 + (len * c) / 4, ce = s0 + (len * (c + 1)) / 4;
    float num = 0.f, den = 0.f;
#pragma unroll 4
    for (int n = cs; n < ce; n++) {
        float wn = wsc[n];
        num = fmaf(wn, (float)x[(size_t)n * HD + f], num);
        den += wn;
    }
    float* dst = y0p + (size_t)(g * 4 + c) * 257;
    dst[f] = num;
    if (f == 0) dst[256] = den;
}

__global__ __launch_bounds__(128) void mlp_k(const float* __restrict__ y0p,
                                             const float* __restrict__ fg,
                                             const float* __restrict__ lw1, const float* __restrict__ lb1,
                                             const float* __restrict__ lw2, const float* __restrict__ lb2,
                                             const float* __restrict__ lw3, const float* __restrict__ lb3,
                                             float* __restrict__ out) {
    __shared__ float y0s[272];
    __shared__ float y1s[128];
    int g = blockIdx.x, t = threadIdx.x;
    const float* p0 = y0p + (size_t)(g * 4 + 0) * 257;
    const float* p1 = y0p + (size_t)(g * 4 + 1) * 257;
    const float* p2 = y0p + (size_t)(g * 4 + 2) * 257;
    const float* p3 = y0p + (size_t)(g * 4 + 3) * 257;
    float den = p0[256] + p1[256] + p2[256] + p3[256];
    float invden = 1.f / fmaxf(den, 1e-9f);
    for (int i = t; i < 256; i += 128)
        y0s[i] = (p0[i] + p1[i] + p2[i] + p3[i]) * invden;
    if (t < EXTRA) y0s[256 + t] = fg[g * EXTRA + t];
    __syncthreads();
    float acc = lb1[t];
    for (int k = 0; k < 272; k++) acc = fmaf(y0s[k], lw1[k * 128 + t], acc);
    y1s[t] = selu_f(acc);
    __syncthreads();
    if (t < 64) {
        float a2 = lb2[t];
        for (int k = 0; k < 128; k++) a2 = fmaf(y1s[k], lw2[k * 64 + t], a2);
        float v2 = selu_f(a2);
        float p = v2 * lw3[t];
#pragma unroll
        for (int off = 1; off < 64; off <<= 1) p += __shfl_xor(p, off, 64);
        if (t == 0) out[g] = p + lb3[0];
    }
}

extern "C" void kernel_launch(void* const* d_in, const int* in_sizes, int n_in,
                              void* d_out, int out_size, void* d_ws, size_t ws_size,
                              hipStream_t stream) {
    const int* src = (const int*)d_in[0];
    const int* dst = (const int*)d_in[1];
    const int* node_graph = (const int*)d_in[2];
    const float* feats_node = (const float*)d_in[3];
    const float* feats_graph = (const float*)d_in[4];
    const float* W1 = (const float*)d_in[5];
    const float* al1 = (const float*)d_in[6];
    const float* ar1 = (const float*)d_in[7];
    const float* bg1 = (const float*)d_in[8];
    const float* W2 = (const float*)d_in[9];
    const float* al2 = (const float*)d_in[10];
    const float* ar2 = (const float*)d_in[11];
    const float* bg2 = (const float*)d_in[12];
    const float* W3 = (const float*)d_in[13];
    const float* al3 = (const float*)d_in[14];
    const float* ar3 = (const float*)d_in[15];
    const float* bg3 = (const float*)d_in[16];
    const float* sw = (const float*)d_in[17];
    const float* sb = (const float*)d_in[18];
    const float* lw1 = (const float*)d_in[19];
    const float* lb1 = (const float*)d_in[20];
    const float* lw2 = (const float*)d_in[21];
    const float* lb2 = (const float*)d_in[22];
    const float* lw3 = (const float*)d_in[23];
    const float* lb3 = (const float*)d_in[24];
    float* out = (float*)d_out;

    char* ws = (char*)d_ws;
    size_t off = 0;
    auto alloc = [&](size_t bytes) -> char* {
        char* p = ws + off;
        off += (bytes + 255) & ~(size_t)255;
        return p;
    };
    _Float16* xhi = (_Float16*)alloc((size_t)N_NODES * HD * 2);
    _Float16* hhi = (_Float16*)alloc((size_t)N_NODES * HD * 2);
    _Float16* W1hi = (_Float16*)alloc((size_t)F_IN * HD * 2);
    _Float16* W1lo = (_Float16*)alloc((size_t)F_IN * HD * 2);
    _Float16* W2hi = (_Float16*)alloc((size_t)HD * HD * 2);
    _Float16* W2lo = (_Float16*)alloc((size_t)HD * HD * 2);
    _Float16* W3hi = (_Float16*)alloc((size_t)HD * HD * 2);
    _Float16* W3lo = (_Float16*)alloc((size_t)HD * HD * 2);
    float* el = (float*)alloc((size_t)N_NODES * 4 * 4);
    float* er = (float*)alloc((size_t)N_NODES * 4 * 4);
    float* wsc = (float*)alloc((size_t)N_NODES * 4);
    float* y0p = (float*)alloc((size_t)N_GRAPHS * 4 * 257 * 4);
    int* hist = (int*)alloc((size_t)N_NODES * 4);
    int* row_ptr = (int*)alloc((size_t)(N_NODES + 1) * 4);
    int* cursor = (int*)alloc((size_t)N_NODES * 4);
    int* csr_src = (int*)alloc((size_t)N_EDGES * 4);
    int* gstart = (int*)alloc((size_t)(N_GRAPHS + 1) * 4);
    int* bsums = (int*)alloc(256 * 4);
    (void)ws_size; (void)in_sizes; (void)n_in; (void)out_size;

    hipMemsetAsync(hist, 0, (size_t)N_NODES * 4, stream);

    // fused: hist (random atomics) || weight splits + graph bounds
    histprep_k<<<EDGE_BLOCKS + 579, 256, 0, stream>>>(dst, hist, W1, W2, W3,
                                                      W1hi, W1lo, W2hi, W2lo, W3hi, W3lo,
                                                      node_graph, gstart);
    int nb = (N_NODES + SCAN_BLOCK - 1) / SCAN_BLOCK;  // 196 <= 256
    scan1_k<<<nb, SCAN_BLOCK, 0, stream>>>(hist, row_ptr, bsums);
    scan23_k<<<(N_NODES + 255) / 256, 256, 0, stream>>>(row_ptr, bsums, cursor, nb);

    dim3 ggrid(HD / 128, (N_NODES + 63) / 64);
    int g1blocks = (HD / 128) * ((N_NODES + 63) / 64);  // 3126
    int nwb = (N_NODES + 3) / 4;

    // layer-1 GEMM with embedded edge-scatter prologue (2 edges/thread)
    gemm1s_k<<<g1blocks, 256, 0, stream>>>(src, dst, cursor, csr_src,
                                           feats_node, W1hi, W1lo, al1, ar1, hhi, el, er);
    gat_aggregate_k<0><<<nwb, 256, 0, stream>>>(hhi, el, er, csr_src, row_ptr, bg1, xhi, nullptr, nullptr, nullptr);
    // layer 2 (A = f16 hi-only, 2-term, double-buffered LDS)
    gemm_k<HD, false, 2><<<ggrid, 256, 0, stream>>>((const void*)xhi, nullptr, W2hi, W2lo, al2, ar2, hhi, el, er, N_NODES);
    gat_aggregate_k<0><<<nwb, 256, 0, stream>>>(hhi, el, er, csr_src, row_ptr, bg2, xhi, nullptr, nullptr, nullptr);
    // layer 3 (A = f16 hi-only, 2-term, double-buffered LDS; f16 out + fused sigmoid score)
    gemm_k<HD, false, 2><<<ggrid, 256, 0, stream>>>((const void*)xhi, nullptr, W3hi, W3lo, al3, ar3, hhi, el, er, N_NODES);
    gat_aggregate_k<1><<<nwb, 256, 0, stream>>>(hhi, el, er, csr_src, row_ptr, bg3, xhi, sw, sb, wsc);

    // readout (4 partials/graph, f16 x) + MLP
    readout_part_k<<<N_GRAPHS * 4, 256, 0, stream>>>(xhi, wsc, gstart, y0p);
    mlp_k<<<N_GRAPHS, 128, 0, stream>>>(y0p, feats_graph, lw1, lb1, lw2, lb2, lw3, lb3, out);
}

// Round 9
// 813.399 us; speedup vs baseline: 1.0504x; 1.0239x over previous
//
#include <hip/hip_runtime.h>

#define N_NODES 100000
#define N_EDGES 1600000
#define N_GRAPHS 512
#define F_IN 64
#define HD 256
#define EXTRA 16
#define SCAN_BLOCK 512
#define EDGE_BLOCKS 6250  // (N_EDGES+255)/256

typedef float f32x4 __attribute__((ext_vector_type(4)));
typedef _Float16 f16x4 __attribute__((ext_vector_type(4)));
typedef _Float16 f16x8 __attribute__((ext_vector_type(8)));

__device__ __forceinline__ float selu_f(float x) {
    const float a = 1.6732632423543772f, sc = 1.0507009873554805f;
    return x > 0.f ? sc * x : sc * a * (__expf(x) - 1.f);
}

// ---------------- CSR build ----------------
__global__ __launch_bounds__(SCAN_BLOCK) void scan1_k(const int* __restrict__ hist,
                                                      int* __restrict__ row_ptr,
                                                      int* __restrict__ bsums) {
    __shared__ int sm[SCAN_BLOCK];
    int t = threadIdx.x;
    int i = blockIdx.x * SCAN_BLOCK + t;
    int v = (i < N_NODES) ? hist[i] : 0;
    sm[t] = v;
    __syncthreads();
    for (int off = 1; off < SCAN_BLOCK; off <<= 1) {
        int add = (t >= off) ? sm[t - off] : 0;
        __syncthreads();
        sm[t] += add;
        __syncthreads();
    }
    if (i < N_NODES) row_ptr[i] = sm[t] - v;
    if (t == SCAN_BLOCK - 1) bsums[blockIdx.x] = sm[t];
}

// merged scan2+scan3: each block re-scans the (<=256) block sums in LDS,
// finalizes row_ptr AND initializes cursor = row_ptr.
__global__ __launch_bounds__(256) void scan23_k(int* __restrict__ row_ptr, const int* __restrict__ bsums,
                                                int* __restrict__ cursor, int nb) {
    __shared__ int bs[256];
    int t = threadIdx.x;
    bs[t] = (t < nb) ? bsums[t] : 0;
    __syncthreads();
    for (int off = 1; off < 256; off <<= 1) {
        int add = (t >= off) ? bs[t - off] : 0;
        __syncthreads();
        bs[t] += add;
        __syncthreads();
    }
    int i = blockIdx.x * 256 + t;
    if (i < N_NODES) {
        int b = i / SCAN_BLOCK;
        int p = b > 0 ? bs[b - 1] : 0;
        int r = row_ptr[i] + p;
        row_ptr[i] = r;
        cursor[i] = r;
    }
    if (i == 0) row_ptr[N_NODES] = N_EDGES;
}

// ---------------- fused: hist (random atomics, LDS-free) || weight splits + graph bounds ----------------
__device__ __forceinline__ void wsplit(const float* __restrict__ W, _Float16* __restrict__ Wh,
                                       _Float16* __restrict__ Wl, int idx, int K) {
    int n = idx / K, k = idx - n * K;
    float w = W[(size_t)k * HD + n];
    _Float16 hi = (_Float16)w;
    Wh[idx] = hi;
    Wl[idx] = (_Float16)(w - (float)hi);
}

__global__ __launch_bounds__(256) void histprep_k(const int* __restrict__ dst, int* __restrict__ hist,
                                                  const float* __restrict__ W1,
                                                  const float* __restrict__ W2,
                                                  const float* __restrict__ W3,
                                                  _Float16* __restrict__ W1h, _Float16* __restrict__ W1l,
                                                  _Float16* __restrict__ W2h, _Float16* __restrict__ W2l,
                                                  _Float16* __restrict__ W3h, _Float16* __restrict__ W3l,
                                                  const int* __restrict__ node_graph,
                                                  int* __restrict__ gstart) {
    int bid = blockIdx.x, t = threadIdx.x;
    if (bid < EDGE_BLOCKS) {
        int j = bid * 256 + t;
        if (j < N_EDGES) atomicAdd(&hist[dst[j]], 1);
        return;
    }
    int b = bid - EDGE_BLOCKS;
    if (b < 64) {
        wsplit(W1, W1h, W1l, b * 256 + t, F_IN);
    } else if (b < 320) {
        wsplit(W2, W2h, W2l, (b - 64) * 256 + t, HD);
    } else if (b < 576) {
        wsplit(W3, W3h, W3l, (b - 320) * 256 + t, HD);
    } else {
        int g = (b - 576) * 256 + t;
        if (g > N_GRAPHS) return;
        int lo = 0, hi = N_NODES;
        while (lo < hi) {
            int mid = (lo + hi) >> 1;
            if (node_graph[mid] < g) lo = mid + 1; else hi = mid;
        }
        gstart[g] = lo;
    }
}

// ---------------- split-f16 MFMA GEMM body ----------------
// ATERMS==3: A split hi+lo (ah*bh + ah*bl + alo*bh). ATERMS==2: A is f16-only (ah*bh + ah*bl).
// BN==128: 2 col-blocks per row panel (layer 1). BN==256: ONE block per 64-row panel -> A
// fetched once (was twice), barriers per output halved, and each wave owns exactly one head
// so the el/er epilogue needs no cross-wave combine.
// ctile padded to BN+4: no 4-way bank conflict on f16x8 epilogue reads.
template <int K, bool F32A, int ATERMS, int BN>
__device__ __forceinline__ void gemm_body(int bx, int by,
                                          const void* __restrict__ Aptr,
                                          const _Float16* __restrict__ Alo_p,
                                          const _Float16* __restrict__ Bt_hi,
                                          const _Float16* __restrict__ Bt_lo,
                                          const float* __restrict__ al,
                                          const float* __restrict__ ar,
                                          _Float16* __restrict__ Chi,
                                          float* __restrict__ el,
                                          float* __restrict__ er, int M) {
    const int BM = 64, LDP = 40, LDC = BN + 4;
    constexpr int NF = BN / 64;   // 16-col MFMA frags per wave
    constexpr int NC = BN / 64;   // B staging chunks (256 thr x f16x8 = BN*32/NC elems)
    constexpr int ASZ = BM * LDP * 2;
    constexpr int BSZ = BN * LDP * 2;
    constexpr int STG = ASZ * (ATERMS == 3 ? 2 : 1) + 2 * BSZ;
    constexpr int CTB = BM * LDC * 2;
    constexpr int SMB = STG > CTB ? STG : CTB;
    __shared__ __align__(16) char smem[SMB];
    __shared__ float pl[4][64];
    __shared__ float pr[4][64];
    _Float16 (*Ash)[LDP] = (_Float16 (*)[LDP])smem;
    _Float16 (*Asl)[LDP] = (_Float16 (*)[LDP])(smem + ASZ);  // deref'd only when ATERMS==3
    _Float16 (*Bsh)[LDP] = (_Float16 (*)[LDP])(smem + ASZ * (ATERMS == 3 ? 2 : 1));
    _Float16 (*Bsl)[LDP] = (_Float16 (*)[LDP])(smem + ASZ * (ATERMS == 3 ? 2 : 1) + BSZ);
    _Float16 (*ctile)[LDC] = (_Float16 (*)[LDC])smem;

    int tid = threadIdx.x;
    int w = tid >> 6, lane = tid & 63;
    int q = lane >> 4, l16 = lane & 15;
    int row0 = by * BM, col0 = bx * BN;
    f32x4 acc[4][NF] = {};

    int ar_ = tid >> 2, ao = (tid & 3) * 8;
    f16x8 rAh, rAl, rBh[NC], rBl[NC];

    auto load_tile = [&](int k0) {
        int gr = row0 + ar_;
        if constexpr (F32A) {
            const float* A32 = (const float*)Aptr;
            float vv[8] = {};
            if (gr < M) {
                float4 va = *(const float4*)(A32 + (size_t)gr * K + k0 + ao);
                float4 vb = *(const float4*)(A32 + (size_t)gr * K + k0 + ao + 4);
                vv[0] = va.x; vv[1] = va.y; vv[2] = va.z; vv[3] = va.w;
                vv[4] = vb.x; vv[5] = vb.y; vv[6] = vb.z; vv[7] = vb.w;
            }
            f16x8 h, l;
#pragma unroll
            for (int i = 0; i < 8; i++) {
                h[i] = (_Float16)vv[i];
                l[i] = (_Float16)(vv[i] - (float)h[i]);
            }
            rAh = h; rAl = l;
        } else {
            const _Float16* Ahi = (const _Float16*)Aptr;
            f16x8 vh = {};
            if (gr < M) {
                vh = *(const f16x8*)(Ahi + (size_t)gr * K + k0 + ao);
                if constexpr (ATERMS == 3) rAl = *(const f16x8*)(Alo_p + (size_t)gr * K + k0 + ao);
            } else if constexpr (ATERMS == 3) {
                rAl = f16x8{};
            }
            rAh = vh;
        }
#pragma unroll
        for (int c = 0; c < NC; c++) {
            int cc = tid + c * 256;
            int br = cc >> 2, bo = (cc & 3) * 8;
            int gb = col0 + br;
            rBh[c] = *(const f16x8*)(Bt_hi + (size_t)gb * K + k0 + bo);
            rBl[c] = *(const f16x8*)(Bt_lo + (size_t)gb * K + k0 + bo);
        }
    };
    auto store_tile = [&]() {
        *(f16x8*)&Ash[ar_][ao] = rAh;
        if constexpr (ATERMS == 3) *(f16x8*)&Asl[ar_][ao] = rAl;
#pragma unroll
        for (int c = 0; c < NC; c++) {
            int cc = tid + c * 256;
            int br = cc >> 2, bo = (cc & 3) * 8;
            *(f16x8*)&Bsh[br][bo] = rBh[c];
            *(f16x8*)&Bsl[br][bo] = rBl[c];
        }
    };

    load_tile(0);
    store_tile();
    __syncthreads();

    for (int k0 = 0; k0 < K; k0 += 32) {
        bool more = (k0 + 32) < K;
        if (more) load_tile(k0 + 32);

        f16x8 ah[4], alo2[4], bh[NF], bl[NF];
#pragma unroll
        for (int mf = 0; mf < 4; mf++) {
            int m = mf * 16 + l16;
            ah[mf] = *(const f16x8*)&Ash[m][q * 8];
            if constexpr (ATERMS == 3) alo2[mf] = *(const f16x8*)&Asl[m][q * 8];
        }
#pragma unroll
        for (int nf = 0; nf < NF; nf++) {
            int n = w * (16 * NF) + nf * 16 + l16;
            bh[nf] = *(const f16x8*)&Bsh[n][q * 8];
            bl[nf] = *(const f16x8*)&Bsl[n][q * 8];
        }
#pragma unroll
        for (int mf = 0; mf < 4; mf++)
#pragma unroll
            for (int nf = 0; nf < NF; nf++) {
                acc[mf][nf] = __builtin_amdgcn_mfma_f32_16x16x32_f16(ah[mf], bh[nf], acc[mf][nf], 0, 0, 0);
                acc[mf][nf] = __builtin_amdgcn_mfma_f32_16x16x32_f16(ah[mf], bl[nf], acc[mf][nf], 0, 0, 0);
                if constexpr (ATERMS == 3)
                    acc[mf][nf] = __builtin_amdgcn_mfma_f32_16x16x32_f16(alo2[mf], bh[nf], acc[mf][nf], 0, 0, 0);
            }
        if (more) {
            __syncthreads();
            store_tile();
            __syncthreads();
        }
    }

    __syncthreads();  // staging reads drained before ctile overwrite

    float alv[NF], arv[NF];
#pragma unroll
    for (int nf = 0; nf < NF; nf++) {
        int hh, d;
        if constexpr (BN == 128) { hh = (col0 >> 6) + (w >> 1); d = (w & 1) * 32 + nf * 16 + l16; }
        else                     { hh = w;                      d = nf * 16 + l16; }
        alv[nf] = al[hh * 64 + d];
        arv[nf] = ar[hh * 64 + d];
    }
#pragma unroll
    for (int mf = 0; mf < 4; mf++) {
#pragma unroll
        for (int i = 0; i < 4; i++) {
            int rl = mf * 16 + q * 4 + i;
            float e_l = 0.f, e_r = 0.f;
#pragma unroll
            for (int nf = 0; nf < NF; nf++) {
                float v = acc[mf][nf][i];
                ctile[rl][w * (16 * NF) + nf * 16 + l16] = (_Float16)v;
                e_l = fmaf(v, alv[nf], e_l);
                e_r = fmaf(v, arv[nf], e_r);
            }
#pragma unroll
            for (int off = 1; off < 16; off <<= 1) {
                e_l += __shfl_xor(e_l, off, 64);
                e_r += __shfl_xor(e_r, off, 64);
            }
            if (l16 == 0) {
                pl[w][rl] = e_l;
                pr[w][rl] = e_r;
            }
        }
    }
    __syncthreads();
    constexpr int TPR = BN / 8;  // threads per ctile row
#pragma unroll
    for (int j = 0; j < (BM * BN) / (256 * 8); j++) {
        int c = tid + j * 256;
        int rr2 = c / TPR, co = (c % TPR) * 8;
        int gr = row0 + rr2;
        if (gr < M)
            *(f16x8*)(Chi + (size_t)gr * HD + col0 + co) = *(const f16x8*)&ctile[rr2][co];
    }
    if constexpr (BN == 128) {
        int h2 = (tid >> 6) & 1, rr = tid & 63;
        int grow = row0 + rr;
        if (grow < M) {
            if (tid < 128) el[(size_t)grow * 4 + (col0 >> 6) + h2] = pl[2 * h2][rr] + pl[2 * h2 + 1][rr];
            else           er[(size_t)grow * 4 + (col0 >> 6) + h2] = pr[2 * h2][rr] + pr[2 * h2 + 1][rr];
        }
    } else {
        int rr = tid & 63, hd = tid >> 6;
        int grow = row0 + rr;
        if (grow < M) {
            el[(size_t)grow * 4 + hd] = pl[hd][rr];
            er[(size_t)grow * 4 + hd] = pr[hd][rr];
        }
    }
}

// standalone GEMM wrapper (layers 2/3: full-width 64x256 tile)
template <int K, bool F32A, int ATERMS, int BN>
__global__ __launch_bounds__(256) void gemm_k(const void* __restrict__ Aptr,
                                              const _Float16* __restrict__ Alo_p,
                                              const _Float16* __restrict__ Bt_hi,
                                              const _Float16* __restrict__ Bt_lo,
                                              const float* __restrict__ al,
                                              const float* __restrict__ ar,
                                              _Float16* __restrict__ Chi,
                                              float* __restrict__ el,
                                              float* __restrict__ er, int M) {
    gemm_body<K, F32A, ATERMS, BN>(blockIdx.x, blockIdx.y, Aptr, Alo_p, Bt_hi, Bt_lo, al, ar, Chi, el, er, M);
}

// ---------------- layer-1 GEMM with embedded edge-scatter prologue ----------------
__global__ __launch_bounds__(256) void gemm1s_k(const int* __restrict__ src,
                                                const int* __restrict__ dst,
                                                int* __restrict__ cursor,
                                                int* __restrict__ csr_src,
                                                const float* __restrict__ feats_node,
                                                const _Float16* __restrict__ W1h,
                                                const _Float16* __restrict__ W1l,
                                                const float* __restrict__ al1,
                                                const float* __restrict__ ar1,
                                                _Float16* __restrict__ hhi,
                                                float* __restrict__ el,
                                                float* __restrict__ er) {
    int lid = blockIdx.x * 256 + threadIdx.x;  // < 800256
    {
        int j = lid;  // always < N_EDGES
        int r = atomicAdd(&cursor[dst[j]], 1);
        r = r < N_EDGES ? r : N_EDGES - 1;  // replay-safety clamp (no-op in clean run)
        csr_src[r] = src[j];
        int j2 = lid + 800256;
        if (j2 < N_EDGES) {
            int r2 = atomicAdd(&cursor[dst[j2]], 1);
            r2 = r2 < N_EDGES ? r2 : N_EDGES - 1;
            csr_src[r2] = src[j2];
        }
    }
    gemm_body<F_IN, true, 3, 128>(blockIdx.x & 1, blockIdx.x >> 1, (const void*)feats_node, nullptr,
                                  W1h, W1l, al1, ar1, hhi, el, er, N_NODES);
}

// ---------------- GAT aggregation (8-pair ring pipeline, f16 output both modes) ----------------
// Aggregation lane layout:
//   eo = lane>>5  : which edge of a pair this half-wave handles
//   fl = lane&31  : feature-lane, covers features [fl*8, fl*8+8)  (head = fl>>3)
template <int OUT>
__global__ __launch_bounds__(256) void gat_aggregate_k(const _Float16* __restrict__ hb,
                                                       const float* __restrict__ el,
                                                       const float* __restrict__ er,
                                                       const int* __restrict__ csr_src,
                                                       const int* __restrict__ row_ptr,
                                                       const float* __restrict__ bias,
                                                       _Float16* __restrict__ xhi,
                                                       const float* __restrict__ sw,
                                                       const float* __restrict__ sb,
                                                       float* __restrict__ wsc) {
    __shared__ float wlds[4][64][4];
    __shared__ int snlds[4][64];
    int wv = threadIdx.x >> 6;
    int lane = threadIdx.x & 63;
    int v = blockIdx.x * 4 + wv;
    bool valid = v < N_NODES;
    int vc = valid ? v : 0;
    int rs = row_ptr[vc];
    int deg = valid ? row_ptr[vc + 1] - rs : 0;
    float4 erv = make_float4(0.f, 0.f, 0.f, 0.f);
    if (valid) erv = *(const float4*)(er + (size_t)vc * 4);

    const int eo = lane >> 5;
    const int fl = lane & 31;
    const int headf = fl >> 3;

    float a[8] = {};
    float dw = 0.f;          // per-(parity,head) partial denominator
    float m_h = 0.f, er_h = 0.f;

    if (deg <= 64) {
        float e0 = -1e30f, e1 = -1e30f, e2 = -1e30f, e3 = -1e30f;
        int my_sn = 0;
        if (lane < deg) {
            my_sn = csr_src[rs + lane];
            float4 elv = *(const float4*)(el + (size_t)my_sn * 4);
            float t0 = elv.x + erv.x, t1 = elv.y + erv.y, t2 = elv.z + erv.z, t3 = elv.w + erv.w;
            e0 = t0 > 0.f ? t0 : 0.2f * t0;
            e1 = t1 > 0.f ? t1 : 0.2f * t1;
            e2 = t2 > 0.f ? t2 : 0.2f * t2;
            e3 = t3 > 0.f ? t3 : 0.2f * t3;
        }
        int P = (deg + 1) >> 1;  // pairs; this lane handles edge 2p+eo
        f16x8 hv[8];
        // prologue A: first 4 pairs via shfl (before LDS weights exist)
        int pA = P < 4 ? P : 4;
#pragma unroll
        for (int u = 0; u < 4; u++) {
            if (u < pA) {
                int idx = 2 * u + eo;
                int cidx = idx < deg ? idx : deg - 1;
                int snb = __shfl(my_sn, cidx, 64);
                hv[u] = *(const f16x8*)(hb + (size_t)snb * HD + fl * 8);
            }
        }
        // per-head max reduce (stability); denominator accumulated in the agg loop
        float m0 = e0, m1 = e1, m2 = e2, m3 = e3;
        for (int off = 1; off < deg; off <<= 1) {
            m0 = fmaxf(m0, __shfl_xor(m0, off, 64));
            m1 = fmaxf(m1, __shfl_xor(m1, off, 64));
            m2 = fmaxf(m2, __shfl_xor(m2, off, 64));
            m3 = fmaxf(m3, __shfl_xor(m3, off, 64));
        }
        if (lane < deg) {
            wlds[wv][lane][0] = __expf(e0 - m0);
            wlds[wv][lane][1] = __expf(e1 - m1);
            wlds[wv][lane][2] = __expf(e2 - m2);
            wlds[wv][lane][3] = __expf(e3 - m3);
            snlds[wv][lane] = my_sn;
        }
        // no barrier: wave-private LDS slice

        // prologue B: pairs 4..7 from snlds
        int pB = P < 8 ? P : 8;
#pragma unroll
        for (int u = 4; u < 8; u++) {
            if (u < pB) {
                int idx = 2 * u + eo;
                int cidx = idx < deg ? idx : deg - 1;
                hv[u] = *(const f16x8*)(hb + (size_t)snlds[wv][cidx] * HD + fl * 8);
            }
        }
        // main ring: consume pair p (slot j=p&7), immediately reissue slot for pair p+8
        for (int pb = 0; pb < P; pb += 8) {
#pragma unroll
            for (int j = 0; j < 8; j++) {
                int p = pb + j;
                if (p >= P) break;  // P is wave-uniform
                int idx = 2 * p + eo;
                float w = (idx < deg) ? wlds[wv][idx][headf] : 0.f;
                dw += w;
                f16x8 h = hv[j];
#pragma unroll
                for (int i = 0; i < 8; i++) a[i] = fmaf(w, (float)h[i], a[i]);
                int pn = p + 8;
                if (pn < P) {
                    int idx2 = 2 * pn + eo;
                    int cidx2 = idx2 < deg ? idx2 : deg - 1;
                    hv[j] = *(const f16x8*)(hb + (size_t)snlds[wv][cidx2] * HD + fl * 8);
                }
            }
        }
    } else {
        // rare path (deg > 64): online softmax stats, then pair-edge aggregation with recomputed weights
        float m[4] = {-1e30f, -1e30f, -1e30f, -1e30f};
        float s[4] = {0.f, 0.f, 0.f, 0.f};
        for (int t = lane; t < deg; t += 64) {
            int sn = csr_src[rs + t];
            float4 elv = *(const float4*)(el + (size_t)sn * 4);
            float e[4];
            e[0] = elv.x + erv.x; e[1] = elv.y + erv.y; e[2] = elv.z + erv.z; e[3] = elv.w + erv.w;
#pragma unroll
            for (int hh = 0; hh < 4; hh++) {
                float ev = e[hh] > 0.f ? e[hh] : 0.2f * e[hh];
                float mn = fmaxf(m[hh], ev);
                s[hh] = s[hh] * __expf(m[hh] - mn) + __expf(ev - mn);
                m[hh] = mn;
            }
        }
#pragma unroll
        for (int off = 32; off >= 1; off >>= 1) {
#pragma unroll
            for (int hh = 0; hh < 4; hh++) {
                float mo = __shfl_xor(m[hh], off, 64);
                float so = __shfl_xor(s[hh], off, 64);
                float mn = fmaxf(m[hh], mo);
                s[hh] = s[hh] * __expf(m[hh] - mn) + so * __expf(mo - mn);
                m[hh] = mn;
            }
        }
        m_h = headf == 0 ? m[0] : headf == 1 ? m[1] : headf == 2 ? m[2] : m[3];
        float dh = headf == 0 ? s[0] : headf == 1 ? s[1] : headf == 2 ? s[2] : s[3];
        er_h = headf == 0 ? erv.x : headf == 1 ? erv.y : headf == 2 ? erv.z : erv.w;
        dw = (eo == 0) ? dh : 0.f;  // combine at epilogue reconstructs dh

        for (int t = 0; t < deg; t += 2) {
            int idx = t + eo;
            int cidx = idx < deg ? idx : idx - 1;
            int sn = csr_src[rs + cidx];
            float w = 0.f;
            if (idx < deg) {
                float e = el[(size_t)sn * 4 + headf] + er_h;
                e = e > 0.f ? e : 0.2f * e;
                w = __expf(e - m_h);
            }
            f16x8 hv = *(const f16x8*)(hb + (size_t)sn * HD + fl * 8);
#pragma unroll
            for (int i = 0; i < 8; i++) a[i] = fmaf(w, (float)hv[i], a[i]);
        }
    }

    // combine even/odd halves (lane <-> lane^32) and finish
#pragma unroll
    for (int i = 0; i < 8; i++) a[i] += __shfl_xor(a[i], 32, 64);
    dw += __shfl_xor(dw, 32, 64);
    float inv_den = 1.f / fmaxf(dw, 1e-9f);

    float4 bv0 = *(const float4*)(bias + fl * 8);
    float4 bv1 = *(const float4*)(bias + fl * 8 + 4);
    float o[8];
    o[0] = selu_f(fmaf(a[0], inv_den, bv0.x));
    o[1] = selu_f(fmaf(a[1], inv_den, bv0.y));
    o[2] = selu_f(fmaf(a[2], inv_den, bv0.z));
    o[3] = selu_f(fmaf(a[3], inv_den, bv0.w));
    o[4] = selu_f(fmaf(a[4], inv_den, bv1.x));
    o[5] = selu_f(fmaf(a[5], inv_den, bv1.y));
    o[6] = selu_f(fmaf(a[6], inv_den, bv1.z));
    o[7] = selu_f(fmaf(a[7], inv_den, bv1.w));

    if constexpr (OUT == 0) {
        // hi-only output (f16): eo==0 half stores the full row
        if (valid && eo == 0) {
            f16x8 oh;
#pragma unroll
            for (int i = 0; i < 8; i++) oh[i] = (_Float16)o[i];
            *(f16x8*)(xhi + (size_t)v * HD + fl * 8) = oh;
        }
    } else {
        // layer-3: f16 feature row (halves write + readout fetch) + fused sigmoid score
        float p;
        if (eo == 0) {
            if (valid) {
                f16x4 oh;
                oh.x = (_Float16)o[0]; oh.y = (_Float16)o[1];
                oh.z = (_Float16)o[2]; oh.w = (_Float16)o[3];
                *(f16x4*)(xhi + (size_t)v * HD + fl * 8) = oh;
            }
            float4 sv = *(const float4*)(sw + fl * 8);
            p = o[0] * sv.x + o[1] * sv.y + o[2] * sv.z + o[3] * sv.w;
        } else {
            if (valid) {
                f16x4 oh;
                oh.x = (_Float16)o[4]; oh.y = (_Float16)o[5];
                oh.z = (_Float16)o[6]; oh.w = (_Float16)o[7];
                *(f16x4*)(xhi + (size_t)v * HD + fl * 8 + 4) = oh;
            }
            float4 sv = *(const float4*)(sw + fl * 8 + 4);
            p = o[4] * sv.x + o[5] * sv.y + o[6] * sv.z + o[7] * sv.w;
        }
#pragma unroll
        for (int off = 1; off < 64; off <<= 1) p += __shfl_xor(p, off, 64);
        if (lane == 0 && valid) wsc[v] = 1.f / (1.f + __expf(-(p + sb[0])));
    }
}

// ---------------- readout: 4 chunk-partials per graph (deterministic, f16 x) ----------------
__global__ __launch_bounds__(256) void readout_part_k(const _Float16* __restrict__ x,
                                                      const float* __restrict__ wsc,
                                                      const int* __restrict__ gstart,
                                                      float* __restrict__ y0p) {
    int g = blockIdx.x >> 2, c = blockIdx.x & 3;
    int f = threadIdx.x;
    int s0 = gstart[g], e0 = gstart[g + 1];
    int len = e0 - s0;
    int cs = s0 + (len * c) / 4, ce = s0 + (len * (c + 1)) / 4;
    float num = 0.f, den = 0.f;
#pragma unroll 4
    for (int n = cs; n < ce; n++) {
        float wn = wsc[n];
        num = fmaf(wn, (float)x[(size_t)n * HD + f], num);
        den += wn;
    }
    float* dst = y0p + (size_t)(g * 4 + c) * 257;
    dst[f] = num;
    if (f == 0) dst[256] = den;
}

__global__ __launch_bounds__(128) void mlp_k(const float* __restrict__ y0p,
                                             const float* __restrict__ fg,
                                             const float* __restrict__ lw1, const float* __restrict__ lb1,
                                             const float* __restrict__ lw2, const float* __restrict__ lb2,
                                             const float* __restrict__ lw3, const float* __restrict__ lb3,
                                             float* __restrict__ out) {
    __shared__ float y0s[272];
    __shared__ float y1s[128];
    int g = blockIdx.x, t = threadIdx.x;
    const float* p0 = y0p + (size_t)(g * 4 + 0) * 257;
    const float* p1 = y0p + (size_t)(g * 4 + 1) * 257;
    const float* p2 = y0p + (size_t)(g * 4 + 2) * 257;
    const float* p3 = y0p + (size_t)(g * 4 + 3) * 257;
    float den = p0[256] + p1[256] + p2[256] + p3[256];
    float invden = 1.f / fmaxf(den, 1e-9f);
    for (int i = t; i < 256; i += 128)
        y0s[i] = (p0[i] + p1[i] + p2[i] + p3[i]) * invden;
    if (t < EXTRA) y0s[256 + t] = fg[g * EXTRA + t];
    __syncthreads();
    float acc = lb1[t];
    for (int k = 0; k < 272; k++) acc = fmaf(y0s[k], lw1[k * 128 + t], acc);
    y1s[t] = selu_f(acc);
    __syncthreads();
    if (t < 64) {
        float a2 = lb2[t];
        for (int k = 0; k < 128; k++) a2 = fmaf(y1s[k], lw2[k * 64 + t], a2);
        float v2 = selu_f(a2);
        float p = v2 * lw3[t];
#pragma unroll
        for (int off = 1; off < 64; off <<= 1) p += __shfl_xor(p, off, 64);
        if (t == 0) out[g] = p + lb3[0];
    }
}

extern "C" void kernel_launch(void* const* d_in, const int* in_sizes, int n_in,
                              void* d_out, int out_size, void* d_ws, size_t ws_size,
                              hipStream_t stream) {
    const int* src = (const int*)d_in[0];
    const int* dst = (const int*)d_in[1];
    const int* node_graph = (const int*)d_in[2];
    const float* feats_node = (const float*)d_in[3];
    const float* feats_graph = (const float*)d_in[4];
    const float* W1 = (const float*)d_in[5];
    const float* al1 = (const float*)d_in[6];
    const float* ar1 = (const float*)d_in[7];
    const float* bg1 = (const float*)d_in[8];
    const float* W2 = (const float*)d_in[9];
    const float* al2 = (const float*)d_in[10];
    const float* ar2 = (const float*)d_in[11];
    const float* bg2 = (const float*)d_in[12];
    const float* W3 = (const float*)d_in[13];
    const float* al3 = (const float*)d_in[14];
    const float* ar3 = (const float*)d_in[15];
    const float* bg3 = (const float*)d_in[16];
    const float* sw = (const float*)d_in[17];
    const float* sb = (const float*)d_in[18];
    const float* lw1 = (const float*)d_in[19];
    const float* lb1 = (const float*)d_in[20];
    const float* lw2 = (const float*)d_in[21];
    const float* lb2 = (const float*)d_in[22];
    const float* lw3 = (const float*)d_in[23];
    const float* lb3 = (const float*)d_in[24];
    float* out = (float*)d_out;

    char* ws = (char*)d_ws;
    size_t off = 0;
    auto alloc = [&](size_t bytes) -> char* {
        char* p = ws + off;
        off += (bytes + 255) & ~(size_t)255;
        return p;
    };
    _Float16* xhi = (_Float16*)alloc((size_t)N_NODES * HD * 2);
    _Float16* hhi = (_Float16*)alloc((size_t)N_NODES * HD * 2);
    _Float16* W1hi = (_Float16*)alloc((size_t)F_IN * HD * 2);
    _Float16* W1lo = (_Float16*)alloc((size_t)F_IN * HD * 2);
    _Float16* W2hi = (_Float16*)alloc((size_t)HD * HD * 2);
    _Float16* W2lo = (_Float16*)alloc((size_t)HD * HD * 2);
    _Float16* W3hi = (_Float16*)alloc((size_t)HD * HD * 2);
    _Float16* W3lo = (_Float16*)alloc((size_t)HD * HD * 2);
    float* el = (float*)alloc((size_t)N_NODES * 4 * 4);
    float* er = (float*)alloc((size_t)N_NODES * 4 * 4);
    float* wsc = (float*)alloc((size_t)N_NODES * 4);
    float* y0p = (float*)alloc((size_t)N_GRAPHS * 4 * 257 * 4);
    int* hist = (int*)alloc((size_t)N_NODES * 4);
    int* row_ptr = (int*)alloc((size_t)(N_NODES + 1) * 4);
    int* cursor = (int*)alloc((size_t)N_NODES * 4);
    int* csr_src = (int*)alloc((size_t)N_EDGES * 4);
    int* gstart = (int*)alloc((size_t)(N_GRAPHS + 1) * 4);
    int* bsums = (int*)alloc(256 * 4);
    (void)ws_size; (void)in_sizes; (void)n_in; (void)out_size;

    hipMemsetAsync(hist, 0, (size_t)N_NODES * 4, stream);

    // fused: hist (random atomics) || weight splits + graph bounds
    histprep_k<<<EDGE_BLOCKS + 579, 256, 0, stream>>>(dst, hist, W1, W2, W3,
                                                      W1hi, W1lo, W2hi, W2lo, W3hi, W3lo,
                                                      node_graph, gstart);
    int nb = (N_NODES + SCAN_BLOCK - 1) / SCAN_BLOCK;  // 196 <= 256
    scan1_k<<<nb, SCAN_BLOCK, 0, stream>>>(hist, row_ptr, bsums);
    scan23_k<<<(N_NODES + 255) / 256, 256, 0, stream>>>(row_ptr, bsums, cursor, nb);

    int nrp = (N_NODES + 63) / 64;  // 1563 row panels
    int g1blocks = 2 * nrp;         // layer-1 keeps 64x128 tiles (2 col-blocks)
    int nwb = (N_NODES + 3) / 4;

    // layer-1 GEMM with embedded edge-scatter prologue (2 edges/thread)
    gemm1s_k<<<g1blocks, 256, 0, stream>>>(src, dst, cursor, csr_src,
                                           feats_node, W1hi, W1lo, al1, ar1, hhi, el, er);
    gat_aggregate_k<0><<<nwb, 256, 0, stream>>>(hhi, el, er, csr_src, row_ptr, bg1, xhi, nullptr, nullptr, nullptr);
    // layer 2 (A = f16 hi-only, 2-term, 64x256 tile: A fetched once)
    gemm_k<HD, false, 2, 256><<<dim3(1, nrp), 256, 0, stream>>>((const void*)xhi, nullptr, W2hi, W2lo, al2, ar2, hhi, el, er, N_NODES);
    gat_aggregate_k<0><<<nwb, 256, 0, stream>>>(hhi, el, er, csr_src, row_ptr, bg2, xhi, nullptr, nullptr, nullptr);
    // layer 3 (A = f16 hi-only, 2-term, 64x256 tile; f16 out + fused sigmoid score)
    gemm_k<HD, false, 2, 256><<<dim3(1, nrp), 256, 0, stream>>>((const void*)xhi, nullptr, W3hi, W3lo, al3, ar3, hhi, el, er, N_NODES);
    gat_aggregate_k<1><<<nwb, 256, 0, stream>>>(hhi, el, er, csr_src, row_ptr, bg3, xhi, sw, sb, wsc);

    // readout (4 partials/graph, f16 x) + MLP
    readout_part_k<<<N_GRAPHS * 4, 256, 0, stream>>>(xhi, wsc, gstart, y0p);
    mlp_k<<<N_GRAPHS, 128, 0, stream>>>(y0p, feats_graph, lw1, lb1, lw2, lb2, lw3, lb3, out);
}